// Round 1
// baseline (1268.962 us; speedup 1.0000x reference)
//
#include <hip/hip_runtime.h>
#include <hip/hip_bf16.h>

#define NNODES 20000
#define NEDGES 320000

__device__ __forceinline__ unsigned enc_f(float x) {
    unsigned b = __float_as_uint(x);
    return (b & 0x80000000u) ? ~b : (b | 0x80000000u);
}
__device__ __forceinline__ float dec_f(unsigned k) {
    unsigned b = (k & 0x80000000u) ? (k & 0x7FFFFFFFu) : ~k;
    return __uint_as_float(b);
}

// h = X @ W  ([n,K] @ [K,256]) plus per-head attention scores
// s_src[n,h] = sum_c h[n,h,c]*a_src[h,c], same for s_dst.
// Block: 256 threads = one column each, 16 nodes per block.
template <int K>
__global__ __launch_bounds__(256) void node_gemm_attn(
    const float* __restrict__ X, const float* __restrict__ W,
    const float* __restrict__ asl, const float* __restrict__ adl,
    float* __restrict__ H, float* __restrict__ Ssrc, float* __restrict__ Sdst,
    int n) {
    __shared__ float xs[16 * K];
    const int node0 = blockIdx.x * 16;
    const int tid = threadIdx.x;
    for (int idx = tid; idx < 16 * K; idx += 256) {
        int r = idx / K, c = idx % K;
        int node = node0 + r;
        xs[idx] = (node < n) ? X[node * K + c] : 0.f;
    }
    __syncthreads();
    const int col = tid;
    const int head = tid >> 6;
    const int lane = tid & 63;
    const float asv = asl[col];
    const float adv = adl[col];
    float acc[16];
#pragma unroll
    for (int i = 0; i < 16; ++i) acc[i] = 0.f;
#pragma unroll 4
    for (int k = 0; k < K; ++k) {
        float w = W[k * 256 + col];
#pragma unroll
        for (int i = 0; i < 16; ++i) acc[i] += xs[i * K + k] * w;
    }
#pragma unroll 1
    for (int i = 0; i < 16; ++i) {
        int node = node0 + i;
        float vs = acc[i] * asv;
        float vd = acc[i] * adv;
#pragma unroll
        for (int off = 32; off > 0; off >>= 1) {
            vs += __shfl_down(vs, off, 64);
            vd += __shfl_down(vd, off, 64);
        }
        if (node < n) {
            H[node * 256 + col] = acc[i];
            if (lane == 0) {
                Ssrc[node * 4 + head] = vs;
                Sdst[node * 4 + head] = vd;
            }
        }
    }
}

// res = X @ res_W + res_b  ([n,128] @ [128,64])
__global__ __launch_bounds__(256) void node_gemm64(
    const float* __restrict__ X, const float* __restrict__ W,
    const float* __restrict__ bias, float* __restrict__ Out, int n) {
    __shared__ float xs[16 * 128];
    const int node0 = blockIdx.x * 16;
    const int tid = threadIdx.x;
    for (int idx = tid; idx < 16 * 128; idx += 256) {
        int r = idx >> 7, c = idx & 127;
        int node = node0 + r;
        xs[idx] = (node < n) ? X[node * 128 + c] : 0.f;
    }
    __syncthreads();
    const int col = tid & 63;
    const int grp = tid >> 6;  // 4 groups x 4 nodes
    float acc[4] = {0.f, 0.f, 0.f, 0.f};
#pragma unroll 4
    for (int k = 0; k < 128; ++k) {
        float w = W[k * 64 + col];
#pragma unroll
        for (int i = 0; i < 4; ++i) acc[i] += xs[(grp * 4 + i) * 128 + k] * w;
    }
    float bv = bias[col];
#pragma unroll
    for (int i = 0; i < 4; ++i) {
        int node = node0 + grp * 4 + i;
        if (node < n) Out[node * 64 + col] = acc[i] + bv;
    }
}

// Pass 1 over edges: leaky_relu score + segment max (encoded atomicMax)
__global__ __launch_bounds__(256) void edge_max(
    const int* __restrict__ ei, const float* __restrict__ Ssrc,
    const float* __restrict__ Sdst, float* __restrict__ score,
    unsigned* __restrict__ M, int E, int n) {
    int e = blockIdx.x * 256 + threadIdx.x;
    int Etot = E + n;
    if (e >= Etot) return;
    int s, d;
    if (e < E) { s = ei[e]; d = ei[E + e]; } else { s = d = e - E; }
    float4 ss = *(const float4*)&Ssrc[s * 4];
    float4 sd = *(const float4*)&Sdst[d * 4];
    float sc[4] = {ss.x + sd.x, ss.y + sd.y, ss.z + sd.z, ss.w + sd.w};
#pragma unroll
    for (int h = 0; h < 4; ++h) {
        sc[h] = sc[h] > 0.f ? sc[h] : 0.2f * sc[h];
        atomicMax(&M[d * 4 + h], enc_f(sc[h]));
    }
    *(float4*)&score[e * 4] = make_float4(sc[0], sc[1], sc[2], sc[3]);
}

// Pass 2: p = exp(score - m[dst]); z[dst] += p  (score buffer overwritten with p)
__global__ __launch_bounds__(256) void edge_expsum(
    const int* __restrict__ ei, float* __restrict__ score,
    const unsigned* __restrict__ M, float* __restrict__ Z, int E, int n) {
    int e = blockIdx.x * 256 + threadIdx.x;
    int Etot = E + n;
    if (e >= Etot) return;
    int d;
    if (e < E) { d = ei[E + e]; } else { d = e - E; }
    float4 sc = *(const float4*)&score[e * 4];
    uint4 mk = *(const uint4*)&M[d * 4];
    float p0 = __expf(sc.x - dec_f(mk.x));
    float p1 = __expf(sc.y - dec_f(mk.y));
    float p2 = __expf(sc.z - dec_f(mk.z));
    float p3 = __expf(sc.w - dec_f(mk.w));
    *(float4*)&score[e * 4] = make_float4(p0, p1, p2, p3);
    atomicAdd(&Z[d * 4 + 0], p0);
    atomicAdd(&Z[d * 4 + 1], p1);
    atomicAdd(&Z[d * 4 + 2], p2);
    atomicAdd(&Z[d * 4 + 3], p3);
}

// Pass 3: out[dst,c] += 0.25 * sum_h alpha[e,h] * H[src,h,c]  (one wave per edge)
__global__ __launch_bounds__(256) void edge_scatter(
    const int* __restrict__ ei, const float* __restrict__ P,
    const float* __restrict__ Z, const float* __restrict__ H,
    float* __restrict__ OutAcc, int E, int n) {
    int t = blockIdx.x * 256 + threadIdx.x;
    int Etot = E + n;
    int e = t >> 6;
    int lane = t & 63;
    if (e >= Etot) return;
    int s, d;
    if (e < E) { s = ei[e]; d = ei[E + e]; } else { s = d = e - E; }
    float4 p = *(const float4*)&P[e * 4];
    float4 z = *(const float4*)&Z[d * 4];
    float a0 = p.x / z.x, a1 = p.y / z.y, a2 = p.z / z.z, a3 = p.w / z.w;
    const float* hs = H + s * 256;
    float v = a0 * hs[lane] + a1 * hs[64 + lane] + a2 * hs[128 + lane] +
              a3 * hs[192 + lane];
    atomicAdd(&OutAcc[d * 64 + lane], 0.25f * v);
}

// Epilogue: feat = elu(outacc + gat_b + resid)
__global__ __launch_bounds__(256) void node_epilogue(
    const float* __restrict__ OutAcc, const float* __restrict__ gb,
    const float* __restrict__ resid, float* __restrict__ featOut, int n) {
    int t = blockIdx.x * 256 + threadIdx.x;
    if (t >= n * 64) return;
    float v = OutAcc[t] + gb[t & 63] + resid[t];
    featOut[t] = v > 0.f ? v : expm1f(v);
}

// Edge classifier MLP: er=[h[row],h[col]] -> relu(er@Wa+ba) -> relu(t1@Wb+bb+t1) -> @Wc+bc
// Block: 256 threads, 64-edge tile, 4x4 register micro-kernel.
__global__ __launch_bounds__(256) void edge_mlp(
    const int* __restrict__ ei, const float* __restrict__ feat,
    const float* __restrict__ Wa, const float* __restrict__ ba,
    const float* __restrict__ Wb, const float* __restrict__ bb,
    const float* __restrict__ Wc, const float* __restrict__ bc,
    float* __restrict__ out, int E) {
    __shared__ float er_s[64 * 132];
    __shared__ float t1_s[64 * 68];
    const int tid = threadIdx.x;
    const int eBase = blockIdx.x * 64;
    {
        const int j = tid & 63;
        const int eg = tid >> 6;
#pragma unroll 4
        for (int it = 0; it < 16; ++it) {
            int el = it * 4 + eg;
            int e = eBase + el;
            int r = 0, c = 0;
            if (e < E) { r = ei[e]; c = ei[E + e]; }
            er_s[el * 132 + j] = feat[r * 64 + j];
            er_s[el * 132 + 64 + j] = feat[c * 64 + j];
        }
    }
    __syncthreads();
    const int tc = tid & 15, te = tid >> 4;
    const int c0 = tc * 4, e0 = te * 4;
    float acc[4][4];
#pragma unroll
    for (int i = 0; i < 4; ++i)
#pragma unroll
        for (int jj = 0; jj < 4; ++jj) acc[i][jj] = 0.f;

#define FMA_ROW(AR, AV, WV)            \
    AR[0] += (AV) * (WV).x;            \
    AR[1] += (AV) * (WV).y;            \
    AR[2] += (AV) * (WV).z;            \
    AR[3] += (AV) * (WV).w;

#pragma unroll 2
    for (int k0 = 0; k0 < 128; k0 += 4) {
        float4 a0 = *(const float4*)&er_s[(e0 + 0) * 132 + k0];
        float4 a1 = *(const float4*)&er_s[(e0 + 1) * 132 + k0];
        float4 a2 = *(const float4*)&er_s[(e0 + 2) * 132 + k0];
        float4 a3 = *(const float4*)&er_s[(e0 + 3) * 132 + k0];
        float4 w0 = *(const float4*)&Wa[(k0 + 0) * 64 + c0];
        float4 w1 = *(const float4*)&Wa[(k0 + 1) * 64 + c0];
        float4 w2 = *(const float4*)&Wa[(k0 + 2) * 64 + c0];
        float4 w3 = *(const float4*)&Wa[(k0 + 3) * 64 + c0];
        FMA_ROW(acc[0], a0.x, w0) FMA_ROW(acc[0], a0.y, w1)
        FMA_ROW(acc[0], a0.z, w2) FMA_ROW(acc[0], a0.w, w3)
        FMA_ROW(acc[1], a1.x, w0) FMA_ROW(acc[1], a1.y, w1)
        FMA_ROW(acc[1], a1.z, w2) FMA_ROW(acc[1], a1.w, w3)
        FMA_ROW(acc[2], a2.x, w0) FMA_ROW(acc[2], a2.y, w1)
        FMA_ROW(acc[2], a2.z, w2) FMA_ROW(acc[2], a2.w, w3)
        FMA_ROW(acc[3], a3.x, w0) FMA_ROW(acc[3], a3.y, w1)
        FMA_ROW(acc[3], a3.z, w2) FMA_ROW(acc[3], a3.w, w3)
    }
    float4 bav = *(const float4*)&ba[c0];
    float t1r[4][4];
#pragma unroll
    for (int i = 0; i < 4; ++i) {
        t1r[i][0] = fmaxf(acc[i][0] + bav.x, 0.f);
        t1r[i][1] = fmaxf(acc[i][1] + bav.y, 0.f);
        t1r[i][2] = fmaxf(acc[i][2] + bav.z, 0.f);
        t1r[i][3] = fmaxf(acc[i][3] + bav.w, 0.f);
        *(float4*)&t1_s[(e0 + i) * 68 + c0] =
            make_float4(t1r[i][0], t1r[i][1], t1r[i][2], t1r[i][3]);
    }
    __syncthreads();
    float acc2[4][4];
#pragma unroll
    for (int i = 0; i < 4; ++i)
#pragma unroll
        for (int jj = 0; jj < 4; ++jj) acc2[i][jj] = 0.f;
#pragma unroll 2
    for (int k0 = 0; k0 < 64; k0 += 4) {
        float4 a0 = *(const float4*)&t1_s[(e0 + 0) * 68 + k0];
        float4 a1 = *(const float4*)&t1_s[(e0 + 1) * 68 + k0];
        float4 a2 = *(const float4*)&t1_s[(e0 + 2) * 68 + k0];
        float4 a3 = *(const float4*)&t1_s[(e0 + 3) * 68 + k0];
        float4 w0 = *(const float4*)&Wb[(k0 + 0) * 64 + c0];
        float4 w1 = *(const float4*)&Wb[(k0 + 1) * 64 + c0];
        float4 w2 = *(const float4*)&Wb[(k0 + 2) * 64 + c0];
        float4 w3 = *(const float4*)&Wb[(k0 + 3) * 64 + c0];
        FMA_ROW(acc2[0], a0.x, w0) FMA_ROW(acc2[0], a0.y, w1)
        FMA_ROW(acc2[0], a0.z, w2) FMA_ROW(acc2[0], a0.w, w3)
        FMA_ROW(acc2[1], a1.x, w0) FMA_ROW(acc2[1], a1.y, w1)
        FMA_ROW(acc2[1], a1.z, w2) FMA_ROW(acc2[1], a1.w, w3)
        FMA_ROW(acc2[2], a2.x, w0) FMA_ROW(acc2[2], a2.y, w1)
        FMA_ROW(acc2[2], a2.z, w2) FMA_ROW(acc2[2], a2.w, w3)
        FMA_ROW(acc2[3], a3.x, w0) FMA_ROW(acc2[3], a3.y, w1)
        FMA_ROW(acc2[3], a3.z, w2) FMA_ROW(acc2[3], a3.w, w3)
    }
    float4 bbv = *(const float4*)&bb[c0];
    float4 wcv = *(const float4*)&Wc[c0];
    float bcv = bc[0];
#pragma unroll
    for (int i = 0; i < 4; ++i) {
        float t20 = fmaxf(acc2[i][0] + bbv.x + t1r[i][0], 0.f);
        float t21 = fmaxf(acc2[i][1] + bbv.y + t1r[i][1], 0.f);
        float t22 = fmaxf(acc2[i][2] + bbv.z + t1r[i][2], 0.f);
        float t23 = fmaxf(acc2[i][3] + bbv.w + t1r[i][3], 0.f);
        float part = t20 * wcv.x + t21 * wcv.y + t22 * wcv.z + t23 * wcv.w;
        part += __shfl_down(part, 8, 16);
        part += __shfl_down(part, 4, 16);
        part += __shfl_down(part, 2, 16);
        part += __shfl_down(part, 1, 16);
        int e = eBase + e0 + i;
        if (tc == 0 && e < E) out[e] = part + bcv;
    }
#undef FMA_ROW
}

extern "C" void kernel_launch(void* const* d_in, const int* in_sizes, int n_in,
                              void* d_out, int out_size, void* d_ws,
                              size_t ws_size, hipStream_t stream) {
    const float* x = (const float*)d_in[0];
    const int* ei = (const int*)d_in[1];
    const float* Wl[4] = {(const float*)d_in[2], (const float*)d_in[3],
                          (const float*)d_in[4], (const float*)d_in[5]};
    const float* a_src = (const float*)d_in[6];
    const float* a_dst = (const float*)d_in[7];
    const float* gat_b = (const float*)d_in[8];
    const float* res_W = (const float*)d_in[9];
    const float* res_b = (const float*)d_in[10];
    const float* lin_W0 = (const float*)d_in[11];
    const float* lin_b0 = (const float*)d_in[12];
    const float* lin_W1 = (const float*)d_in[13];
    const float* lin_b1 = (const float*)d_in[14];
    const float* lin_W2 = (const float*)d_in[15];
    const float* lin_b2 = (const float*)d_in[16];
    float* out = (float*)d_out;

    const int N = in_sizes[0] / 128;  // 20000
    const int E = in_sizes[1] / 2;    // 320000
    const int Etot = E + N;

    float* ws = (float*)d_ws;
    float* h = ws;                    // N*256
    float* feat = h + (size_t)N * 256;    // N*64
    float* res = feat + (size_t)N * 64;   // N*64
    float* ssrc = res + (size_t)N * 64;   // N*4
    float* sdst = ssrc + (size_t)N * 4;   // N*4
    unsigned* m = (unsigned*)(sdst + (size_t)N * 4);  // N*4
    float* z = (float*)m + (size_t)N * 4;             // N*4
    float* outacc = z + (size_t)N * 4;                // N*64
    float* score = outacc + (size_t)N * 64;           // Etot*4

    const int nodeBlocks = (N + 15) / 16;
    const int edgeBlocks = (Etot + 255) / 256;
    const int scatBlocks = (Etot + 3) / 4;
    const int featBlocks = (N * 64 + 255) / 256;

    // residual projection (layer 0)
    node_gemm64<<<nodeBlocks, 256, 0, stream>>>(x, res_W, res_b, res, N);

    for (int i = 0; i < 4; ++i) {
        if (i == 0)
            node_gemm_attn<128><<<nodeBlocks, 256, 0, stream>>>(
                x, Wl[0], a_src, a_dst, h, ssrc, sdst, N);
        else
            node_gemm_attn<64><<<nodeBlocks, 256, 0, stream>>>(
                feat, Wl[i], a_src + i * 256, a_dst + i * 256, h, ssrc, sdst, N);
        // zero m, z, outacc (contiguous region: N*4 + N*4 + N*64 floats)
        hipMemsetAsync(m, 0, (size_t)N * 72 * sizeof(float), stream);
        edge_max<<<edgeBlocks, 256, 0, stream>>>(ei, ssrc, sdst, score, m, E, N);
        edge_expsum<<<edgeBlocks, 256, 0, stream>>>(ei, score, m, z, E, N);
        edge_scatter<<<scatBlocks, 256, 0, stream>>>(ei, score, z, h, outacc, E, N);
        const float* resid = (i == 0) ? res : feat;
        node_epilogue<<<featBlocks, 256, 0, stream>>>(outacc, gat_b + i * 64,
                                                      resid, feat, N);
    }

    edge_mlp<<<(E + 63) / 64, 256, 0, stream>>>(ei, feat, lin_W0, lin_b0,
                                                lin_W1, lin_b1, lin_W2, lin_b2,
                                                out, E);
}

// Round 2
// 612.604 us; speedup vs baseline: 2.0714x; 2.0714x over previous
//
#include <hip/hip_runtime.h>
#include <hip/hip_bf16.h>

#define NSLOPE 0.2f

// ---------------- CSR build (edge_index is constant; rebuilt each call) -----

__global__ __launch_bounds__(256) void hist_deg(const int* __restrict__ ei,
                                                int* __restrict__ deg, int E,
                                                int n) {
    int t = blockIdx.x * 256 + threadIdx.x;
    int Etot = E + n;
    if (t >= Etot) return;
    int d = (t < E) ? ei[E + t] : (t - E);
    atomicAdd(&deg[d], 1);
}

// single-block scan: rowstart (exclusive prefix) + cursor copy + rowstart[n]
__global__ __launch_bounds__(256) void scan_deg(const int* __restrict__ deg,
                                                int* __restrict__ rowstart,
                                                int* __restrict__ cursor,
                                                int n) {
    __shared__ int partial[256];
    const int t = threadIdx.x;
    const int chunk = (n + 255) / 256;
    const int lo = t * chunk;
    const int hi = min(lo + chunk, n);
    int s = 0;
    for (int i = lo; i < hi; ++i) s += deg[i];
    partial[t] = s;
    __syncthreads();
    for (int off = 1; off < 256; off <<= 1) {
        int v = (t >= off) ? partial[t - off] : 0;
        __syncthreads();
        partial[t] += v;
        __syncthreads();
    }
    int run = partial[t] - s;  // exclusive base
    for (int i = lo; i < hi; ++i) {
        rowstart[i] = run;
        cursor[i] = run;
        run += deg[i];
    }
    if (t == 255) rowstart[n] = partial[255];
}

__global__ __launch_bounds__(256) void fill_csr(const int* __restrict__ ei,
                                                int* __restrict__ cursor,
                                                int* __restrict__ csr, int E,
                                                int n) {
    int t = blockIdx.x * 256 + threadIdx.x;
    int Etot = E + n;
    if (t >= Etot) return;
    int s, d;
    if (t < E) { s = ei[t]; d = ei[E + t]; } else { s = d = t - E; }
    int pos = atomicAdd(&cursor[d], 1);
    csr[pos] = s;
}

// ---------------- node GEMMs ------------------------------------------------

// h = X @ W  ([n,K] @ [K,256]) + per-head attention scores
template <int K>
__global__ __launch_bounds__(256) void node_gemm_attn(
    const float* __restrict__ X, const float* __restrict__ W,
    const float* __restrict__ asl, const float* __restrict__ adl,
    float* __restrict__ H, float* __restrict__ Ssrc, float* __restrict__ Sdst,
    int n) {
    __shared__ float xs[16 * K];
    const int node0 = blockIdx.x * 16;
    const int tid = threadIdx.x;
    for (int idx = tid; idx < 16 * K; idx += 256) {
        int r = idx / K, c = idx % K;
        int node = node0 + r;
        xs[idx] = (node < n) ? X[node * K + c] : 0.f;
    }
    __syncthreads();
    const int col = tid;
    const int head = tid >> 6;
    const int lane = tid & 63;
    const float asv = asl[col];
    const float adv = adl[col];
    float acc[16];
#pragma unroll
    for (int i = 0; i < 16; ++i) acc[i] = 0.f;
#pragma unroll 2
    for (int k0 = 0; k0 < K; k0 += 4) {
        float w0 = W[(k0 + 0) * 256 + col];
        float w1 = W[(k0 + 1) * 256 + col];
        float w2 = W[(k0 + 2) * 256 + col];
        float w3 = W[(k0 + 3) * 256 + col];
#pragma unroll
        for (int i = 0; i < 16; ++i) {
            float4 xv = *(const float4*)&xs[i * K + k0];
            acc[i] += xv.x * w0 + xv.y * w1 + xv.z * w2 + xv.w * w3;
        }
    }
#pragma unroll 1
    for (int i = 0; i < 16; ++i) {
        int node = node0 + i;
        float vs = acc[i] * asv;
        float vd = acc[i] * adv;
#pragma unroll
        for (int off = 32; off > 0; off >>= 1) {
            vs += __shfl_down(vs, off, 64);
            vd += __shfl_down(vd, off, 64);
        }
        if (node < n) {
            H[node * 256 + col] = acc[i];
            if (lane == 0) {
                Ssrc[node * 4 + head] = vs;
                Sdst[node * 4 + head] = vd;
            }
        }
    }
}

// Out = X @ W (+bias)  ([n,K] @ [K,64]); bias may be null
template <int K>
__global__ __launch_bounds__(256) void node_gemmN(
    const float* __restrict__ X, const float* __restrict__ W,
    const float* __restrict__ bias, float* __restrict__ Out, int n) {
    __shared__ float xs[16 * K];
    const int node0 = blockIdx.x * 16;
    const int tid = threadIdx.x;
    for (int idx = tid; idx < 16 * K; idx += 256) {
        int r = idx / K, c = idx % K;
        int node = node0 + r;
        xs[idx] = (node < n) ? X[node * K + c] : 0.f;
    }
    __syncthreads();
    const int col = tid & 63;
    const int grp = tid >> 6;  // 4 groups x 4 nodes
    float acc[4] = {0.f, 0.f, 0.f, 0.f};
#pragma unroll 2
    for (int k0 = 0; k0 < K; k0 += 4) {
        float w0 = W[(k0 + 0) * 64 + col];
        float w1 = W[(k0 + 1) * 64 + col];
        float w2 = W[(k0 + 2) * 64 + col];
        float w3 = W[(k0 + 3) * 64 + col];
#pragma unroll
        for (int i = 0; i < 4; ++i) {
            float4 xv = *(const float4*)&xs[(grp * 4 + i) * K + k0];
            acc[i] += xv.x * w0 + xv.y * w1 + xv.z * w2 + xv.w * w3;
        }
    }
    float bv = bias ? bias[col] : 0.f;
#pragma unroll
    for (int i = 0; i < 4; ++i) {
        int node = node0 + grp * 4 + i;
        if (node < n) Out[node * 64 + col] = acc[i] + bv;
    }
}

// ---------------- fused GAT softmax + aggregate + epilogue (gather, no atomics)
// One wave per dst node. Pass 1: per-head max. Pass 2: accumulate
// uh[h][c] = sum_e p[e,h]*H[src,h,c] and z[h]; out = mean_h uh/z + b + resid; ELU.
__global__ __launch_bounds__(256) void gat_gather(
    const int* __restrict__ csr, const int* __restrict__ rowstart,
    const float* __restrict__ Ssrc, const float* __restrict__ Sdst,
    const float* __restrict__ H, const float* __restrict__ gb,
    const float* __restrict__ resid, float* __restrict__ featOut, int n) {
    const int wid = threadIdx.x >> 6;
    const int lane = threadIdx.x & 63;
    const int node = blockIdx.x * 4 + wid;
    if (node >= n) return;
    const int start = rowstart[node];
    const int end = rowstart[node + 1];
    const float4 sd = *(const float4*)&Sdst[node * 4];

    // pass 1: per-head max (lane = el*4 + h)
    const int el = lane >> 2;
    const int h = lane & 3;
    const float sdh = (h == 0) ? sd.x : (h == 1) ? sd.y : (h == 2) ? sd.z : sd.w;
    float mval = -1e30f;
    for (int b = start; b < end; b += 16) {
        int e = b + el;
        if (e < end) {
            int s = csr[e];
            float sc = Ssrc[s * 4 + h] + sdh;
            sc = sc > 0.f ? sc : NSLOPE * sc;
            mval = fmaxf(mval, sc);
        }
    }
#pragma unroll
    for (int off = 4; off < 64; off <<= 1)
        mval = fmaxf(mval, __shfl_xor(mval, off, 64));
    const float m0 = __shfl(mval, 0, 64);
    const float m1 = __shfl(mval, 1, 64);
    const float m2 = __shfl(mval, 2, 64);
    const float m3 = __shfl(mval, 3, 64);

    // pass 2: lane = channel c
    float u0 = 0.f, u1 = 0.f, u2 = 0.f, u3 = 0.f;
    float z0 = 0.f, z1 = 0.f, z2 = 0.f, z3 = 0.f;
#pragma unroll 2
    for (int e = start; e < end; ++e) {
        int s = csr[e];
        float4 ss = *(const float4*)&Ssrc[s * 4];
        float c0 = ss.x + sd.x, c1 = ss.y + sd.y, c2 = ss.z + sd.z,
              c3 = ss.w + sd.w;
        c0 = c0 > 0.f ? c0 : NSLOPE * c0;
        c1 = c1 > 0.f ? c1 : NSLOPE * c1;
        c2 = c2 > 0.f ? c2 : NSLOPE * c2;
        c3 = c3 > 0.f ? c3 : NSLOPE * c3;
        float p0 = __expf(c0 - m0), p1 = __expf(c1 - m1);
        float p2 = __expf(c2 - m2), p3 = __expf(c3 - m3);
        const float* hp = H + (size_t)s * 256;
        u0 += p0 * hp[lane];
        u1 += p1 * hp[64 + lane];
        u2 += p2 * hp[128 + lane];
        u3 += p3 * hp[192 + lane];
        z0 += p0; z1 += p1; z2 += p2; z3 += p3;
    }
    float val = 0.25f * (u0 / z0 + u1 / z1 + u2 / z2 + u3 / z3) + gb[lane] +
                resid[(size_t)node * 64 + lane];
    featOut[(size_t)node * 64 + lane] = val > 0.f ? val : expm1f(val);
}

// ---------------- edge classifier: t1 = relu(U[row]+V[col]); t2 = relu(t1@Wb+bb+t1);
// out = t2@Wc + bc.  64-edge tile, 4x4 micro-kernel.
__global__ __launch_bounds__(256) void edge_mlp2(
    const int* __restrict__ ei, const float* __restrict__ U,
    const float* __restrict__ V, const float* __restrict__ Wb,
    const float* __restrict__ bb, const float* __restrict__ Wc,
    const float* __restrict__ bc, float* __restrict__ out, int E) {
    __shared__ float t1_s[64 * 68];
    const int tid = threadIdx.x;
    const int eBase = blockIdx.x * 64;
    {
        const int j = tid & 63;
        const int eg = tid >> 6;
#pragma unroll 4
        for (int it = 0; it < 16; ++it) {
            int el = it * 4 + eg;
            int e = eBase + el;
            int r = 0, c = 0;
            if (e < E) { r = ei[e]; c = ei[E + e]; }
            float v = U[(size_t)r * 64 + j] + V[(size_t)c * 64 + j];
            t1_s[el * 68 + j] = fmaxf(v, 0.f);
        }
    }
    __syncthreads();
    const int tc = tid & 15, te = tid >> 4;
    const int c0 = tc * 4, e0 = te * 4;
    float acc2[4][4];
#pragma unroll
    for (int i = 0; i < 4; ++i)
#pragma unroll
        for (int jj = 0; jj < 4; ++jj) acc2[i][jj] = 0.f;

#define FMA_ROW(AR, AV, WV)            \
    AR[0] += (AV) * (WV).x;            \
    AR[1] += (AV) * (WV).y;            \
    AR[2] += (AV) * (WV).z;            \
    AR[3] += (AV) * (WV).w;

#pragma unroll 2
    for (int k0 = 0; k0 < 64; k0 += 4) {
        float4 a0 = *(const float4*)&t1_s[(e0 + 0) * 68 + k0];
        float4 a1 = *(const float4*)&t1_s[(e0 + 1) * 68 + k0];
        float4 a2 = *(const float4*)&t1_s[(e0 + 2) * 68 + k0];
        float4 a3 = *(const float4*)&t1_s[(e0 + 3) * 68 + k0];
        float4 w0 = *(const float4*)&Wb[(k0 + 0) * 64 + c0];
        float4 w1 = *(const float4*)&Wb[(k0 + 1) * 64 + c0];
        float4 w2 = *(const float4*)&Wb[(k0 + 2) * 64 + c0];
        float4 w3 = *(const float4*)&Wb[(k0 + 3) * 64 + c0];
        FMA_ROW(acc2[0], a0.x, w0) FMA_ROW(acc2[0], a0.y, w1)
        FMA_ROW(acc2[0], a0.z, w2) FMA_ROW(acc2[0], a0.w, w3)
        FMA_ROW(acc2[1], a1.x, w0) FMA_ROW(acc2[1], a1.y, w1)
        FMA_ROW(acc2[1], a1.z, w2) FMA_ROW(acc2[1], a1.w, w3)
        FMA_ROW(acc2[2], a2.x, w0) FMA_ROW(acc2[2], a2.y, w1)
        FMA_ROW(acc2[2], a2.z, w2) FMA_ROW(acc2[2], a2.w, w3)
        FMA_ROW(acc2[3], a3.x, w0) FMA_ROW(acc2[3], a3.y, w1)
        FMA_ROW(acc2[3], a3.z, w2) FMA_ROW(acc2[3], a3.w, w3)
    }
#undef FMA_ROW
    float4 bbv = *(const float4*)&bb[c0];
    float4 wcv = *(const float4*)&Wc[c0];
    float bcv = bc[0];
#pragma unroll
    for (int i = 0; i < 4; ++i) {
        float4 t1r = *(const float4*)&t1_s[(e0 + i) * 68 + c0];
        float t20 = fmaxf(acc2[i][0] + bbv.x + t1r.x, 0.f);
        float t21 = fmaxf(acc2[i][1] + bbv.y + t1r.y, 0.f);
        float t22 = fmaxf(acc2[i][2] + bbv.z + t1r.z, 0.f);
        float t23 = fmaxf(acc2[i][3] + bbv.w + t1r.w, 0.f);
        float part = t20 * wcv.x + t21 * wcv.y + t22 * wcv.z + t23 * wcv.w;
        part += __shfl_down(part, 8, 16);
        part += __shfl_down(part, 4, 16);
        part += __shfl_down(part, 2, 16);
        part += __shfl_down(part, 1, 16);
        int e = eBase + e0 + i;
        if (tc == 0 && e < E) out[e] = part + bcv;
    }
}

extern "C" void kernel_launch(void* const* d_in, const int* in_sizes, int n_in,
                              void* d_out, int out_size, void* d_ws,
                              size_t ws_size, hipStream_t stream) {
    const float* x = (const float*)d_in[0];
    const int* ei = (const int*)d_in[1];
    const float* Wl[4] = {(const float*)d_in[2], (const float*)d_in[3],
                          (const float*)d_in[4], (const float*)d_in[5]};
    const float* a_src = (const float*)d_in[6];
    const float* a_dst = (const float*)d_in[7];
    const float* gat_b = (const float*)d_in[8];
    const float* res_W = (const float*)d_in[9];
    const float* res_b = (const float*)d_in[10];
    const float* lin_W0 = (const float*)d_in[11];
    const float* lin_b0 = (const float*)d_in[12];
    const float* lin_W1 = (const float*)d_in[13];
    const float* lin_b1 = (const float*)d_in[14];
    const float* lin_W2 = (const float*)d_in[15];
    const float* lin_b2 = (const float*)d_in[16];
    float* out = (float*)d_out;

    const int N = in_sizes[0] / 128;  // 20000
    const int E = in_sizes[1] / 2;    // 320000
    const int Etot = E + N;

    float* ws = (float*)d_ws;
    float* h = ws;                          // N*256 (reused for U/V at end)
    float* feat = h + (size_t)N * 256;      // N*64
    float* res = feat + (size_t)N * 64;     // N*64
    float* ssrc = res + (size_t)N * 64;     // N*4
    float* sdst = ssrc + (size_t)N * 4;     // N*4
    int* deg = (int*)(sdst + (size_t)N * 4);  // N
    int* rowstart = deg + N;                // N+1
    int* cursor = rowstart + N + 1;         // N
    int* csr = cursor + N;                  // Etot
    float* U = h;                           // alias: h dead after layers
    float* V = h + (size_t)N * 64;

    const int nodeBlocks = (N + 15) / 16;
    const int edgeBlocks = (Etot + 255) / 256;
    const int gathBlocks = (N + 3) / 4;

    // CSR build (no-op dependence on layer compute; runs first)
    hipMemsetAsync(deg, 0, (size_t)N * sizeof(int), stream);
    hist_deg<<<edgeBlocks, 256, 0, stream>>>(ei, deg, E, N);
    scan_deg<<<1, 256, 0, stream>>>(deg, rowstart, cursor, N);
    fill_csr<<<edgeBlocks, 256, 0, stream>>>(ei, cursor, csr, E, N);

    // residual projection (layer 0)
    node_gemmN<128><<<nodeBlocks, 256, 0, stream>>>(x, res_W, res_b, res, N);

    for (int i = 0; i < 4; ++i) {
        if (i == 0)
            node_gemm_attn<128><<<nodeBlocks, 256, 0, stream>>>(
                x, Wl[0], a_src, a_dst, h, ssrc, sdst, N);
        else
            node_gemm_attn<64><<<nodeBlocks, 256, 0, stream>>>(
                feat, Wl[i], a_src + i * 256, a_dst + i * 256, h, ssrc, sdst, N);
        const float* resid = (i == 0) ? res : feat;
        gat_gather<<<gathBlocks, 256, 0, stream>>>(
            csr, rowstart, ssrc, sdst, h, gat_b + i * 64, resid, feat, N);
    }

    // edge classifier: U = feat@W0_top + b0, V = feat@W0_bot
    node_gemmN<64><<<nodeBlocks, 256, 0, stream>>>(feat, lin_W0, lin_b0, U, N);
    node_gemmN<64><<<nodeBlocks, 256, 0, stream>>>(feat, lin_W0 + 64 * 64,
                                                   nullptr, V, N);
    edge_mlp2<<<(E + 63) / 64, 256, 0, stream>>>(ei, U, V, lin_W1, lin_b1,
                                                 lin_W2, lin_b2, out, E);
}

// Round 3
// 546.164 us; speedup vs baseline: 2.3234x; 1.1216x over previous
//
#include <hip/hip_runtime.h>
#include <hip/hip_bf16.h>

#define NSLOPE 0.2f

typedef short bf16x8 __attribute__((ext_vector_type(8)));
typedef float f32x4 __attribute__((ext_vector_type(4)));

__device__ __forceinline__ unsigned short f2b(float f) {
    unsigned u = __float_as_uint(f);
    unsigned r = (u + 0x7FFFu + ((u >> 16) & 1u)) >> 16;
    return (unsigned short)r;
}
__device__ __forceinline__ float b2f_lo(unsigned w) {
    return __uint_as_float(w << 16);
}
__device__ __forceinline__ float b2f_hi(unsigned w) {
    return __uint_as_float(w & 0xFFFF0000u);
}

// ---------------- CSR build -------------------------------------------------

__global__ __launch_bounds__(256) void hist_deg(const int* __restrict__ ei,
                                                int* __restrict__ deg, int E,
                                                int n) {
    int t = blockIdx.x * 256 + threadIdx.x;
    int Etot = E + n;
    if (t >= Etot) return;
    int d = (t < E) ? ei[E + t] : (t - E);
    atomicAdd(&deg[d], 1);
}

__global__ __launch_bounds__(256) void scan_deg(const int* __restrict__ deg,
                                                int* __restrict__ rowstart,
                                                int* __restrict__ cursor,
                                                int n) {
    __shared__ int partial[256];
    const int t = threadIdx.x;
    const int chunk = (n + 255) / 256;
    const int lo = t * chunk;
    const int hi = min(lo + chunk, n);
    int s = 0;
    for (int i = lo; i < hi; ++i) s += deg[i];
    partial[t] = s;
    __syncthreads();
    for (int off = 1; off < 256; off <<= 1) {
        int v = (t >= off) ? partial[t - off] : 0;
        __syncthreads();
        partial[t] += v;
        __syncthreads();
    }
    int run = partial[t] - s;
    for (int i = lo; i < hi; ++i) {
        rowstart[i] = run;
        cursor[i] = run;
        run += deg[i];
    }
    if (t == 255) rowstart[n] = partial[255];
}

__global__ __launch_bounds__(256) void fill_csr(const int* __restrict__ ei,
                                                int* __restrict__ cursor,
                                                int* __restrict__ csr, int E,
                                                int n) {
    int t = blockIdx.x * 256 + threadIdx.x;
    int Etot = E + n;
    if (t >= Etot) return;
    int s, d;
    if (t < E) { s = ei[t]; d = ei[E + t]; } else { s = d = t - E; }
    int pos = atomicAdd(&cursor[d], 1);
    csr[pos] = s;
}

// ---------------- weight prep: fp32 [K][NC] -> bf16 [NC][K] (transposed) ----

__global__ __launch_bounds__(256) void prep_weights(
    const float* __restrict__ W0, const float* __restrict__ W1,
    const float* __restrict__ W2, const float* __restrict__ W3,
    const float* __restrict__ resW, const float* __restrict__ linW0,
    short* __restrict__ Wt0, short* __restrict__ Wt1, short* __restrict__ Wt2,
    short* __restrict__ Wt3, short* __restrict__ WtR, short* __restrict__ WtU,
    short* __restrict__ WtV) {
    const float* src;
    short* dst;
    int K, NC, rowoff = 0;
    switch (blockIdx.x) {
        case 0: src = W0; dst = Wt0; K = 128; NC = 256; break;
        case 1: src = W1; dst = Wt1; K = 64; NC = 256; break;
        case 2: src = W2; dst = Wt2; K = 64; NC = 256; break;
        case 3: src = W3; dst = Wt3; K = 64; NC = 256; break;
        case 4: src = resW; dst = WtR; K = 128; NC = 64; break;
        case 5: src = linW0; dst = WtU; K = 64; NC = 64; break;
        default: src = linW0; dst = WtV; K = 64; NC = 64; rowoff = 64; break;
    }
    for (int idx = threadIdx.x; idx < K * NC; idx += 256) {
        int k = idx / NC, nn = idx - k * NC;
        dst[nn * K + k] = (short)f2b(src[(k + rowoff) * NC + nn]);
    }
}

__global__ __launch_bounds__(256) void convert_x(const float* __restrict__ x,
                                                 short* __restrict__ xb,
                                                 int total) {
    int idx = (blockIdx.x * 256 + threadIdx.x) * 4;
    if (idx >= total) return;
    float4 v = *(const float4*)(x + idx);
    ushort4 o;
    o.x = f2b(v.x); o.y = f2b(v.y); o.z = f2b(v.z); o.w = f2b(v.w);
    *(ushort4*)(xb + idx) = o;
}

// ---------------- MFMA node GEMM -------------------------------------------
// Xb: [n][K] bf16.  Wt: [NG*16][K] bf16 (transposed weights, k contiguous).
// PACK=true : NG=16, write Hp0[node][64] = pack(h0,h1), Hp1 = pack(h2,h3)
// PACK=false: write Out[node][NG*16] fp32 (+bias)
template <int K, int NG, bool PACK>
__global__ __launch_bounds__(256) void mfma_gemm(
    const short* __restrict__ Xb, const short* __restrict__ Wt,
    const float* __restrict__ bias, unsigned* __restrict__ Hp0,
    unsigned* __restrict__ Hp1, float* __restrict__ Out, int n) {
    constexpr int XSTR = K + 8;   // 16B-aligned row stride, bank-spread
    constexpr int NC = NG * 16;
    __shared__ __align__(16) short Xs[64 * XSTR];
    __shared__ __align__(16) short Ws[NC * 40];  // 32 k + 8 pad per row
    const int tid = threadIdx.x;
    const int nb = blockIdx.x * 64;
    constexpr int CH = K / 8;
    for (int idx = tid; idx < 64 * CH; idx += 256) {
        int row = idx / CH, c = idx - row * CH;
        uint4 v = make_uint4(0, 0, 0, 0);
        if (nb + row < n)
            v = *(const uint4*)(Xb + (size_t)(nb + row) * K + c * 8);
        *(uint4*)(Xs + row * XSTR + c * 8) = v;
    }
    const int wid = tid >> 6;
    const int lane = tid & 63;
    const int t = lane & 15, quad = lane >> 4;
    f32x4 acc[NG];
#pragma unroll
    for (int g = 0; g < NG; ++g) acc[g] = (f32x4){0.f, 0.f, 0.f, 0.f};
#pragma unroll 1
    for (int kc = 0; kc < K / 32; ++kc) {
        __syncthreads();
        for (int idx = tid; idx < NC * 4; idx += 256) {
            int row = idx >> 2, c = idx & 3;
            uint4 v = *(const uint4*)(Wt + (size_t)row * K + kc * 32 + c * 8);
            *(uint4*)(Ws + row * 40 + c * 8) = v;
        }
        __syncthreads();
        bf16x8 a =
            *(const bf16x8*)(Xs + (wid * 16 + t) * XSTR + kc * 32 + quad * 8);
#pragma unroll
        for (int g = 0; g < NG; ++g) {
            bf16x8 b = *(const bf16x8*)(Ws + (g * 16 + t) * 40 + quad * 8);
            acc[g] = __builtin_amdgcn_mfma_f32_16x16x32_bf16(a, b, acc[g], 0, 0, 0);
        }
    }
    // epilogue: C/D layout col = lane&15 (within 16-col group), row = quad*4+reg
    if (PACK) {
#pragma unroll
        for (int r = 0; r < 4; ++r) {
            int node = nb + wid * 16 + quad * 4 + r;
            if (node >= n) continue;
#pragma unroll
            for (int g = 0; g < 4; ++g) {
                unsigned p01 = ((unsigned)f2b(acc[g + 4][r]) << 16) |
                               (unsigned)f2b(acc[g][r]);
                unsigned p23 = ((unsigned)f2b(acc[g + 12][r]) << 16) |
                               (unsigned)f2b(acc[g + 8][r]);
                Hp0[(size_t)node * 64 + g * 16 + t] = p01;
                Hp1[(size_t)node * 64 + g * 16 + t] = p23;
            }
        }
    } else {
        float bv[NG];
#pragma unroll
        for (int g = 0; g < NG; ++g) bv[g] = bias ? bias[g * 16 + t] : 0.f;
#pragma unroll
        for (int r = 0; r < 4; ++r) {
            int node = nb + wid * 16 + quad * 4 + r;
            if (node >= n) continue;
#pragma unroll
            for (int g = 0; g < NG; ++g)
                Out[(size_t)node * NC + g * 16 + t] = acc[g][r] + bv[g];
        }
    }
}

// ---------------- attention scores: s[h] = sum_c h[h][c]*a[h][c] ------------
__global__ __launch_bounds__(256) void attn_scores(
    const unsigned* __restrict__ Hp0, const unsigned* __restrict__ Hp1,
    const float* __restrict__ as, const float* __restrict__ ad,
    float* __restrict__ Ssrc, float* __restrict__ Sdst, int n) {
    const int wid = threadIdx.x >> 6;
    const int lane = threadIdx.x & 63;
    const int node = blockIdx.x * 4 + wid;
    if (node >= n) return;
    unsigned w0 = Hp0[(size_t)node * 64 + lane];
    unsigned w1 = Hp1[(size_t)node * 64 + lane];
    float h0 = b2f_lo(w0), h1 = b2f_hi(w0), h2 = b2f_lo(w1), h3 = b2f_hi(w1);
    float ps0 = h0 * as[lane], ps1 = h1 * as[64 + lane];
    float ps2 = h2 * as[128 + lane], ps3 = h3 * as[192 + lane];
    float pd0 = h0 * ad[lane], pd1 = h1 * ad[64 + lane];
    float pd2 = h2 * ad[128 + lane], pd3 = h3 * ad[192 + lane];
#pragma unroll
    for (int off = 1; off < 64; off <<= 1) {
        ps0 += __shfl_xor(ps0, off, 64);
        ps1 += __shfl_xor(ps1, off, 64);
        ps2 += __shfl_xor(ps2, off, 64);
        ps3 += __shfl_xor(ps3, off, 64);
        pd0 += __shfl_xor(pd0, off, 64);
        pd1 += __shfl_xor(pd1, off, 64);
        pd2 += __shfl_xor(pd2, off, 64);
        pd3 += __shfl_xor(pd3, off, 64);
    }
    if (lane == 0) {
        float4 s = make_float4(ps0, ps1, ps2, ps3);
        float4 d = make_float4(pd0, pd1, pd2, pd3);
        *(float4*)&Ssrc[node * 4] = s;
        *(float4*)&Sdst[node * 4] = d;
    }
}

// ---------------- fused GAT softmax + aggregate + epilogue (gather) ---------
__global__ __launch_bounds__(256) void gat_gather(
    const int* __restrict__ csr, const int* __restrict__ rowstart,
    const float* __restrict__ Ssrc, const float* __restrict__ Sdst,
    const unsigned* __restrict__ Hp0, const unsigned* __restrict__ Hp1,
    const float* __restrict__ gb, const float* __restrict__ resid,
    float* __restrict__ featOut, short* __restrict__ featB, int n) {
    const int wid = threadIdx.x >> 6;
    const int lane = threadIdx.x & 63;
    const int node = blockIdx.x * 4 + wid;
    if (node >= n) return;
    const int start = rowstart[node];
    const int end = rowstart[node + 1];
    const float4 sd = *(const float4*)&Sdst[node * 4];

    // pass 1: per-head max (lane = el*4 + h)
    const int el = lane >> 2;
    const int h = lane & 3;
    const float sdh = (h == 0) ? sd.x : (h == 1) ? sd.y : (h == 2) ? sd.z : sd.w;
    float mval = -1e30f;
    for (int b = start; b < end; b += 16) {
        int e = b + el;
        if (e < end) {
            int s = csr[e];
            float sc = Ssrc[s * 4 + h] + sdh;
            sc = sc > 0.f ? sc : NSLOPE * sc;
            mval = fmaxf(mval, sc);
        }
    }
#pragma unroll
    for (int off = 4; off < 64; off <<= 1)
        mval = fmaxf(mval, __shfl_xor(mval, off, 64));
    const float m0 = __shfl(mval, 0, 64);
    const float m1 = __shfl(mval, 1, 64);
    const float m2 = __shfl(mval, 2, 64);
    const float m3 = __shfl(mval, 3, 64);

    // pass 2: lane = channel
    float u0 = 0.f, u1 = 0.f, u2 = 0.f, u3 = 0.f;
    float z0 = 0.f, z1 = 0.f, z2 = 0.f, z3 = 0.f;
#pragma unroll 2
    for (int e = start; e < end; ++e) {
        int s = csr[e];
        float4 ss = *(const float4*)&Ssrc[s * 4];
        float c0 = ss.x + sd.x, c1 = ss.y + sd.y, c2 = ss.z + sd.z,
              c3 = ss.w + sd.w;
        c0 = c0 > 0.f ? c0 : NSLOPE * c0;
        c1 = c1 > 0.f ? c1 : NSLOPE * c1;
        c2 = c2 > 0.f ? c2 : NSLOPE * c2;
        c3 = c3 > 0.f ? c3 : NSLOPE * c3;
        float p0 = __expf(c0 - m0), p1 = __expf(c1 - m1);
        float p2 = __expf(c2 - m2), p3 = __expf(c3 - m3);
        unsigned w0 = Hp0[(size_t)s * 64 + lane];
        unsigned w1 = Hp1[(size_t)s * 64 + lane];
        u0 += p0 * b2f_lo(w0);
        u1 += p1 * b2f_hi(w0);
        u2 += p2 * b2f_lo(w1);
        u3 += p3 * b2f_hi(w1);
        z0 += p0; z1 += p1; z2 += p2; z3 += p3;
    }
    float val = 0.25f * (u0 / z0 + u1 / z1 + u2 / z2 + u3 / z3) + gb[lane] +
                resid[(size_t)node * 64 + lane];
    val = val > 0.f ? val : expm1f(val);
    featOut[(size_t)node * 64 + lane] = val;
    featB[(size_t)node * 64 + lane] = (short)f2b(val);
}

// ---------------- edge classifier -------------------------------------------
__global__ __launch_bounds__(256) void edge_mlp2(
    const int* __restrict__ ei, const float* __restrict__ U,
    const float* __restrict__ V, const float* __restrict__ Wb,
    const float* __restrict__ bb, const float* __restrict__ Wc,
    const float* __restrict__ bc, float* __restrict__ out, int E) {
    __shared__ float t1_s[64 * 68];
    const int tid = threadIdx.x;
    const int eBase = blockIdx.x * 64;
    {
        const int j = tid & 63;
        const int eg = tid >> 6;
#pragma unroll 4
        for (int it = 0; it < 16; ++it) {
            int el = it * 4 + eg;
            int e = eBase + el;
            int r = 0, c = 0;
            if (e < E) { r = ei[e]; c = ei[E + e]; }
            float v = U[(size_t)r * 64 + j] + V[(size_t)c * 64 + j];
            t1_s[el * 68 + j] = fmaxf(v, 0.f);
        }
    }
    __syncthreads();
    const int tc = tid & 15, te = tid >> 4;
    const int c0 = tc * 4, e0 = te * 4;
    float acc2[4][4];
#pragma unroll
    for (int i = 0; i < 4; ++i)
#pragma unroll
        for (int jj = 0; jj < 4; ++jj) acc2[i][jj] = 0.f;

#define FMA_ROW(AR, AV, WV)            \
    AR[0] += (AV) * (WV).x;            \
    AR[1] += (AV) * (WV).y;            \
    AR[2] += (AV) * (WV).z;            \
    AR[3] += (AV) * (WV).w;

#pragma unroll 2
    for (int k0 = 0; k0 < 64; k0 += 4) {
        float4 a0 = *(const float4*)&t1_s[(e0 + 0) * 68 + k0];
        float4 a1 = *(const float4*)&t1_s[(e0 + 1) * 68 + k0];
        float4 a2 = *(const float4*)&t1_s[(e0 + 2) * 68 + k0];
        float4 a3 = *(const float4*)&t1_s[(e0 + 3) * 68 + k0];
        float4 w0 = *(const float4*)&Wb[(k0 + 0) * 64 + c0];
        float4 w1 = *(const float4*)&Wb[(k0 + 1) * 64 + c0];
        float4 w2 = *(const float4*)&Wb[(k0 + 2) * 64 + c0];
        float4 w3 = *(const float4*)&Wb[(k0 + 3) * 64 + c0];
        FMA_ROW(acc2[0], a0.x, w0) FMA_ROW(acc2[0], a0.y, w1)
        FMA_ROW(acc2[0], a0.z, w2) FMA_ROW(acc2[0], a0.w, w3)
        FMA_ROW(acc2[1], a1.x, w0) FMA_ROW(acc2[1], a1.y, w1)
        FMA_ROW(acc2[1], a1.z, w2) FMA_ROW(acc2[1], a1.w, w3)
        FMA_ROW(acc2[2], a2.x, w0) FMA_ROW(acc2[2], a2.y, w1)
        FMA_ROW(acc2[2], a2.z, w2) FMA_ROW(acc2[2], a2.w, w3)
        FMA_ROW(acc2[3], a3.x, w0) FMA_ROW(acc2[3], a3.y, w1)
        FMA_ROW(acc2[3], a3.z, w2) FMA_ROW(acc2[3], a3.w, w3)
    }
#undef FMA_ROW
    float4 bbv = *(const float4*)&bb[c0];
    float4 wcv = *(const float4*)&Wc[c0];
    float bcv = bc[0];
#pragma unroll
    for (int i = 0; i < 4; ++i) {
        float4 t1r = *(const float4*)&t1_s[(e0 + i) * 68 + c0];
        float t20 = fmaxf(acc2[i][0] + bbv.x + t1r.x, 0.f);
        float t21 = fmaxf(acc2[i][1] + bbv.y + t1r.y, 0.f);
        float t22 = fmaxf(acc2[i][2] + bbv.z + t1r.z, 0.f);
        float t23 = fmaxf(acc2[i][3] + bbv.w + t1r.w, 0.f);
        float part = t20 * wcv.x + t21 * wcv.y + t22 * wcv.z + t23 * wcv.w;
        part += __shfl_down(part, 8, 16);
        part += __shfl_down(part, 4, 16);
        part += __shfl_down(part, 2, 16);
        part += __shfl_down(part, 1, 16);
        int e = eBase + e0 + i;
        if (tc == 0 && e < E) out[e] = part + bcv;
    }
}

extern "C" void kernel_launch(void* const* d_in, const int* in_sizes, int n_in,
                              void* d_out, int out_size, void* d_ws,
                              size_t ws_size, hipStream_t stream) {
    const float* x = (const float*)d_in[0];
    const int* ei = (const int*)d_in[1];
    const float* W0 = (const float*)d_in[2];
    const float* W1 = (const float*)d_in[3];
    const float* W2 = (const float*)d_in[4];
    const float* W3 = (const float*)d_in[5];
    const float* a_src = (const float*)d_in[6];
    const float* a_dst = (const float*)d_in[7];
    const float* gat_b = (const float*)d_in[8];
    const float* res_W = (const float*)d_in[9];
    const float* res_b = (const float*)d_in[10];
    const float* lin_W0 = (const float*)d_in[11];
    const float* lin_b0 = (const float*)d_in[12];
    const float* lin_W1 = (const float*)d_in[13];
    const float* lin_b1 = (const float*)d_in[14];
    const float* lin_W2 = (const float*)d_in[15];
    const float* lin_b2 = (const float*)d_in[16];
    float* out = (float*)d_out;

    const int N = in_sizes[0] / 128;  // 20000
    const int E = in_sizes[1] / 2;    // 320000
    const int Etot = E + N;

    float* ws = (float*)d_ws;
    unsigned* Hp0 = (unsigned*)ws;                     // N*64 u32
    unsigned* Hp1 = Hp0 + (size_t)N * 64;              // N*64 u32
    float* feat = (float*)(Hp1 + (size_t)N * 64);      // N*64
    float* res = feat + (size_t)N * 64;                // N*64
    short* xb = (short*)(res + (size_t)N * 64);        // N*128 bf16
    short* featb = xb;                                 // alias (N*64 bf16)
    float* Ssrc = (float*)(xb + (size_t)N * 128);      // N*4
    float* Sdst = Ssrc + (size_t)N * 4;                // N*4
    short* Wt0 = (short*)(Sdst + (size_t)N * 4);       // 256*128
    short* Wt1 = Wt0 + 256 * 128;                      // 256*64
    short* Wt2 = Wt1 + 256 * 64;
    short* Wt3 = Wt2 + 256 * 64;
    short* WtR = Wt3 + 256 * 64;                       // 64*128
    short* WtU = WtR + 64 * 128;                       // 64*64
    short* WtV = WtU + 64 * 64;                        // 64*64
    int* deg = (int*)(WtV + 64 * 64);                  // N
    int* rowstart = deg + N;                           // N+1
    int* cursor = rowstart + N + 1;                    // N
    int* csr = cursor + N;                             // Etot
    float* U = (float*)Hp0;                            // alias, N*64
    float* V = (float*)Hp1;                            // alias, N*64

    const int gemmBlocks = (N + 63) / 64;
    const int edgeBlocks = (Etot + 255) / 256;
    const int nodeW = (N + 3) / 4;
    const short* Wts[4] = {Wt0, Wt1, Wt2, Wt3};

    // CSR build
    hipMemsetAsync(deg, 0, (size_t)N * sizeof(int), stream);
    hist_deg<<<edgeBlocks, 256, 0, stream>>>(ei, deg, E, N);
    scan_deg<<<1, 256, 0, stream>>>(deg, rowstart, cursor, N);
    fill_csr<<<edgeBlocks, 256, 0, stream>>>(ei, cursor, csr, E, N);

    // weight prep + x conversion
    prep_weights<<<7, 256, 0, stream>>>(W0, W1, W2, W3, res_W, lin_W0, Wt0,
                                        Wt1, Wt2, Wt3, WtR, WtU, WtV);
    convert_x<<<(N * 128 / 4 + 255) / 256, 256, 0, stream>>>(x, xb, N * 128);

    for (int i = 0; i < 4; ++i) {
        if (i == 0)
            mfma_gemm<128, 16, true><<<gemmBlocks, 256, 0, stream>>>(
                xb, Wt0, nullptr, Hp0, Hp1, nullptr, N);
        else
            mfma_gemm<64, 16, true><<<gemmBlocks, 256, 0, stream>>>(
                featb, Wts[i], nullptr, Hp0, Hp1, nullptr, N);
        attn_scores<<<nodeW, 256, 0, stream>>>(Hp0, Hp1, a_src + i * 256,
                                               a_dst + i * 256, Ssrc, Sdst, N);
        if (i == 0)  // residual projection (reads xb; must precede gather's featb write)
            mfma_gemm<128, 4, false><<<gemmBlocks, 256, 0, stream>>>(
                xb, WtR, res_b, nullptr, nullptr, res, N);
        const float* resid = (i == 0) ? res : feat;
        gat_gather<<<nodeW, 256, 0, stream>>>(csr, rowstart, Ssrc, Sdst, Hp0,
                                              Hp1, gat_b + i * 64, resid, feat,
                                              featb, N);
    }

    // edge classifier heads: U = feat@W0_top + b0, V = feat@W0_bot
    mfma_gemm<64, 4, false><<<gemmBlocks, 256, 0, stream>>>(
        featb, WtU, lin_b0, nullptr, nullptr, U, N);
    mfma_gemm<64, 4, false><<<gemmBlocks, 256, 0, stream>>>(
        featb, WtV, nullptr, nullptr, nullptr, V, N);
    edge_mlp2<<<(E + 63) / 64, 256, 0, stream>>>(ei, U, V, lin_W1, lin_b1,
                                                 lin_W2, lin_b2, out, E);
}

// Round 4
// 466.702 us; speedup vs baseline: 2.7190x; 1.1703x over previous
//
#include <hip/hip_runtime.h>
#include <hip/hip_bf16.h>

#define NSLOPE 0.2f

typedef short bf16x8 __attribute__((ext_vector_type(8)));
typedef float f32x4 __attribute__((ext_vector_type(4)));

__device__ __forceinline__ unsigned short f2b(float f) {
    unsigned u = __float_as_uint(f);
    unsigned r = (u + 0x7FFFu + ((u >> 16) & 1u)) >> 16;
    return (unsigned short)r;
}
__device__ __forceinline__ float b2f_lo(unsigned w) {
    return __uint_as_float(w << 16);
}
__device__ __forceinline__ float b2f_hi(unsigned w) {
    return __uint_as_float(w & 0xFFFF0000u);
}
__device__ __forceinline__ float b2f_s(short s) {
    return __uint_as_float(((unsigned)(unsigned short)s) << 16);
}

// ---------------- CSR build -------------------------------------------------

__global__ __launch_bounds__(256) void hist_deg(const int* __restrict__ ei,
                                                int* __restrict__ deg, int E,
                                                int n) {
    int t = blockIdx.x * 256 + threadIdx.x;
    int Etot = E + n;
    if (t >= Etot) return;
    int d = (t < E) ? ei[E + t] : (t - E);
    atomicAdd(&deg[d], 1);
}

__global__ __launch_bounds__(256) void scan_deg(const int* __restrict__ deg,
                                                int* __restrict__ rowstart,
                                                int* __restrict__ cursor,
                                                int n) {
    __shared__ int partial[256];
    const int t = threadIdx.x;
    const int chunk = (n + 255) / 256;
    const int lo = t * chunk;
    const int hi = min(lo + chunk, n);
    int s = 0;
    for (int i = lo; i < hi; ++i) s += deg[i];
    partial[t] = s;
    __syncthreads();
    for (int off = 1; off < 256; off <<= 1) {
        int v = (t >= off) ? partial[t - off] : 0;
        __syncthreads();
        partial[t] += v;
        __syncthreads();
    }
    int run = partial[t] - s;
    for (int i = lo; i < hi; ++i) {
        rowstart[i] = run;
        cursor[i] = run;
        run += deg[i];
    }
    if (t == 255) rowstart[n] = partial[255];
}

__global__ __launch_bounds__(256) void fill_csr(const int* __restrict__ ei,
                                                int* __restrict__ cursor,
                                                int* __restrict__ csr, int E,
                                                int n) {
    int t = blockIdx.x * 256 + threadIdx.x;
    int Etot = E + n;
    if (t >= Etot) return;
    int s, d;
    if (t < E) { s = ei[t]; d = ei[E + t]; } else { s = d = t - E; }
    int pos = atomicAdd(&cursor[d], 1);
    csr[pos] = s;
}

// ---------------- weight prep: fp32 [K][NC] -> bf16 [NC][K] (transposed) ----

__global__ __launch_bounds__(256) void prep_weights(
    const float* __restrict__ W0, const float* __restrict__ W1,
    const float* __restrict__ W2, const float* __restrict__ W3,
    const float* __restrict__ resW, const float* __restrict__ linW0,
    const float* __restrict__ linW1, short* __restrict__ Wt0,
    short* __restrict__ Wt1, short* __restrict__ Wt2, short* __restrict__ Wt3,
    short* __restrict__ WtR, short* __restrict__ WtU, short* __restrict__ WtV,
    short* __restrict__ WbT) {
    const float* src;
    short* dst;
    int K, NC, rowoff = 0;
    switch (blockIdx.x) {
        case 0: src = W0; dst = Wt0; K = 128; NC = 256; break;
        case 1: src = W1; dst = Wt1; K = 64; NC = 256; break;
        case 2: src = W2; dst = Wt2; K = 64; NC = 256; break;
        case 3: src = W3; dst = Wt3; K = 64; NC = 256; break;
        case 4: src = resW; dst = WtR; K = 128; NC = 64; break;
        case 5: src = linW0; dst = WtU; K = 64; NC = 64; break;
        case 6: src = linW0; dst = WtV; K = 64; NC = 64; rowoff = 64; break;
        default: src = linW1; dst = WbT; K = 64; NC = 64; break;
    }
    for (int idx = threadIdx.x; idx < K * NC; idx += 256) {
        int k = idx / NC, nn = idx - k * NC;
        dst[nn * K + k] = (short)f2b(src[(k + rowoff) * NC + nn]);
    }
}

__global__ __launch_bounds__(256) void convert_x(const float* __restrict__ x,
                                                 short* __restrict__ xb,
                                                 int total) {
    int idx = (blockIdx.x * 256 + threadIdx.x) * 4;
    if (idx >= total) return;
    float4 v = *(const float4*)(x + idx);
    ushort4 o;
    o.x = f2b(v.x); o.y = f2b(v.y); o.z = f2b(v.z); o.w = f2b(v.w);
    *(ushort4*)(xb + idx) = o;
}

// ---------------- MFMA node GEMM -------------------------------------------
// Xb: [n][K] bf16.  Wt: [NG*16][K] bf16 (transposed weights, k contiguous).
// OM=0: OutF[node][NG*16] fp32 (+bias)
// OM=1: NG=16; Hq[node][64] uint2 = (pack(h0,h1), pack(h2,h3)); fused attn
//       scores -> Ssrc/Sdst[node][4]
// OM=2: OutB[node][NG*16] bf16 (+bias)
template <int K, int NG, int OM>
__global__ __launch_bounds__(256) void mfma_gemm(
    const short* __restrict__ Xb, const short* __restrict__ Wt,
    const float* __restrict__ bias, uint2* __restrict__ Hq,
    const float* __restrict__ as_l, const float* __restrict__ ad_l,
    float* __restrict__ Ssrc, float* __restrict__ Sdst,
    float* __restrict__ OutF, short* __restrict__ OutB, int n) {
    constexpr int XSTR = K + 8;   // 16B-aligned row stride, bank-spread
    constexpr int NC = NG * 16;
    __shared__ __align__(16) short Xs[64 * XSTR];
    __shared__ __align__(16) short Ws[NC * 40];  // 32 k + 8 pad per row
    const int tid = threadIdx.x;
    const int nb = blockIdx.x * 64;
    constexpr int CH = K / 8;
    for (int idx = tid; idx < 64 * CH; idx += 256) {
        int row = idx / CH, c = idx - row * CH;
        uint4 v = make_uint4(0, 0, 0, 0);
        if (nb + row < n)
            v = *(const uint4*)(Xb + (size_t)(nb + row) * K + c * 8);
        *(uint4*)(Xs + row * XSTR + c * 8) = v;
    }
    const int wid = tid >> 6;
    const int lane = tid & 63;
    const int t = lane & 15, quad = lane >> 4;
    f32x4 acc[NG];
#pragma unroll
    for (int g = 0; g < NG; ++g) acc[g] = (f32x4){0.f, 0.f, 0.f, 0.f};
#pragma unroll 1
    for (int kc = 0; kc < K / 32; ++kc) {
        __syncthreads();
        for (int idx = tid; idx < NC * 4; idx += 256) {
            int row = idx >> 2, c = idx & 3;
            uint4 v = *(const uint4*)(Wt + (size_t)row * K + kc * 32 + c * 8);
            *(uint4*)(Ws + row * 40 + c * 8) = v;
        }
        __syncthreads();
        bf16x8 a =
            *(const bf16x8*)(Xs + (wid * 16 + t) * XSTR + kc * 32 + quad * 8);
#pragma unroll
        for (int g = 0; g < NG; ++g) {
            bf16x8 b = *(const bf16x8*)(Ws + (g * 16 + t) * 40 + quad * 8);
            acc[g] = __builtin_amdgcn_mfma_f32_16x16x32_bf16(a, b, acc[g], 0, 0, 0);
        }
    }
    // epilogue: C/D layout col = g*16 + t, row(node) = nb + wid*16 + quad*4 + r
    if (OM == 1) {
#pragma unroll
        for (int r = 0; r < 4; ++r) {
            int node = nb + wid * 16 + quad * 4 + r;
            if (node >= n) continue;
#pragma unroll
            for (int g = 0; g < 4; ++g) {
                unsigned p01 = ((unsigned)f2b(acc[g + 4][r]) << 16) |
                               (unsigned)f2b(acc[g][r]);
                unsigned p23 = ((unsigned)f2b(acc[g + 12][r]) << 16) |
                               (unsigned)f2b(acc[g + 8][r]);
                Hq[(size_t)node * 64 + g * 16 + t] = make_uint2(p01, p23);
            }
        }
        // fused attention scores
        float asv[16], adv[16];
#pragma unroll
        for (int G = 0; G < 16; ++G) {
            asv[G] = as_l[G * 16 + t];
            adv[G] = ad_l[G * 16 + t];
        }
#pragma unroll
        for (int r = 0; r < 4; ++r) {
            int node = nb + wid * 16 + quad * 4 + r;
            float pv[8];
#pragma unroll
            for (int h = 0; h < 4; ++h) {
                float ps = 0.f, pd = 0.f;
#pragma unroll
                for (int j = 0; j < 4; ++j) {
                    float a = acc[h * 4 + j][r];
                    ps += a * asv[h * 4 + j];
                    pd += a * adv[h * 4 + j];
                }
                pv[h] = ps;
                pv[4 + h] = pd;
            }
#pragma unroll
            for (int off = 1; off < 16; off <<= 1) {
#pragma unroll
                for (int i = 0; i < 8; ++i) pv[i] += __shfl_xor(pv[i], off, 64);
            }
            if (t == 0 && node < n) {
                *(float4*)&Ssrc[node * 4] =
                    make_float4(pv[0], pv[1], pv[2], pv[3]);
                *(float4*)&Sdst[node * 4] =
                    make_float4(pv[4], pv[5], pv[6], pv[7]);
            }
        }
    } else {
        float bv[NG];
#pragma unroll
        for (int g = 0; g < NG; ++g) bv[g] = bias ? bias[g * 16 + t] : 0.f;
#pragma unroll
        for (int r = 0; r < 4; ++r) {
            int node = nb + wid * 16 + quad * 4 + r;
            if (node >= n) continue;
            if (OM == 0) {
#pragma unroll
                for (int g = 0; g < NG; ++g)
                    OutF[(size_t)node * NC + g * 16 + t] = acc[g][r] + bv[g];
            } else {
#pragma unroll
                for (int g = 0; g < NG; ++g)
                    OutB[(size_t)node * NC + g * 16 + t] =
                        (short)f2b(acc[g][r] + bv[g]);
            }
        }
    }
}

// ---------------- fused GAT softmax + aggregate + epilogue (gather) ---------
__global__ __launch_bounds__(256) void gat_gather(
    const int* __restrict__ csr, const int* __restrict__ rowstart,
    const float* __restrict__ Ssrc, const float* __restrict__ Sdst,
    const uint2* __restrict__ Hq, const float* __restrict__ gb,
    const float* __restrict__ resid, float* __restrict__ featOut,
    short* __restrict__ featB, int n) {
    const int wid = threadIdx.x >> 6;
    const int lane = threadIdx.x & 63;
    const int node = blockIdx.x * 4 + wid;
    if (node >= n) return;
    const int start = rowstart[node];
    const int end = rowstart[node + 1];
    const float4 sd = *(const float4*)&Sdst[node * 4];

    // pass 1: per-head max (lane = el*4 + h)
    const int el = lane >> 2;
    const int h = lane & 3;
    const float sdh = (h == 0) ? sd.x : (h == 1) ? sd.y : (h == 2) ? sd.z : sd.w;
    float mval = -1e30f;
    for (int b = start; b < end; b += 16) {
        int e = b + el;
        if (e < end) {
            int s = csr[e];
            float sc = Ssrc[s * 4 + h] + sdh;
            sc = sc > 0.f ? sc : NSLOPE * sc;
            mval = fmaxf(mval, sc);
        }
    }
#pragma unroll
    for (int off = 4; off < 64; off <<= 1)
        mval = fmaxf(mval, __shfl_xor(mval, off, 64));
    const float m0 = __shfl(mval, 0, 64);
    const float m1 = __shfl(mval, 1, 64);
    const float m2 = __shfl(mval, 2, 64);
    const float m3 = __shfl(mval, 3, 64);

    // pass 2: lane = channel
    float u0 = 0.f, u1 = 0.f, u2 = 0.f, u3 = 0.f;
    float z0 = 0.f, z1 = 0.f, z2 = 0.f, z3 = 0.f;
#pragma unroll 4
    for (int e = start; e < end; ++e) {
        int s = csr[e];
        float4 ss = *(const float4*)&Ssrc[s * 4];
        float c0 = ss.x + sd.x, c1 = ss.y + sd.y, c2 = ss.z + sd.z,
              c3 = ss.w + sd.w;
        c0 = c0 > 0.f ? c0 : NSLOPE * c0;
        c1 = c1 > 0.f ? c1 : NSLOPE * c1;
        c2 = c2 > 0.f ? c2 : NSLOPE * c2;
        c3 = c3 > 0.f ? c3 : NSLOPE * c3;
        float p0 = __expf(c0 - m0), p1 = __expf(c1 - m1);
        float p2 = __expf(c2 - m2), p3 = __expf(c3 - m3);
        uint2 hv = Hq[(size_t)s * 64 + lane];
        u0 += p0 * b2f_lo(hv.x);
        u1 += p1 * b2f_hi(hv.x);
        u2 += p2 * b2f_lo(hv.y);
        u3 += p3 * b2f_hi(hv.y);
        z0 += p0; z1 += p1; z2 += p2; z3 += p3;
    }
    float val = 0.25f * (u0 / z0 + u1 / z1 + u2 / z2 + u3 / z3) + gb[lane] +
                resid[(size_t)node * 64 + lane];
    val = val > 0.f ? val : expm1f(val);
    featOut[(size_t)node * 64 + lane] = val;
    featB[(size_t)node * 64 + lane] = (short)f2b(val);
}

// ---------------- edge classifier (MFMA) ------------------------------------
// t1 = relu(U[row]+V[col]) (bf16 in), t2 = relu(t1@Wb + bb + t1), out = t2@Wc+bc
__global__ __launch_bounds__(256) void edge_mlp3(
    const int* __restrict__ ei, const unsigned* __restrict__ Ub,
    const unsigned* __restrict__ Vb, const short* __restrict__ WbT,
    const float* __restrict__ bb, const float* __restrict__ Wc,
    const float* __restrict__ bc, float* __restrict__ out, int E) {
    __shared__ __align__(16) short t1b[64 * 72];
    __shared__ __align__(16) short wbs[64 * 72];
    const int tid = threadIdx.x;
    const int eBase = blockIdx.x * 64;
    // stage WbT (64x64 bf16) into LDS
    for (int idx = tid; idx < 512; idx += 256) {
        int row = idx >> 3, c = idx & 7;
        *(uint4*)(wbs + row * 72 + c * 8) =
            *(const uint4*)(WbT + row * 64 + c * 8);
    }
    // stage t1 = relu(U[r]+V[c]) bf16; hoist all index loads first
    {
        const int j = tid & 31;   // channel pair
        const int eg = tid >> 5;  // 8 edge groups
        int rr[8], cc[8];
#pragma unroll
        for (int it = 0; it < 8; ++it) {
            int e = eBase + it * 8 + eg;
            rr[it] = (e < E) ? ei[e] : 0;
            cc[it] = (e < E) ? ei[E + e] : 0;
        }
#pragma unroll
        for (int it = 0; it < 8; ++it) {
            unsigned uu = Ub[(size_t)rr[it] * 32 + j];
            unsigned vv = Vb[(size_t)cc[it] * 32 + j];
            float lo = fmaxf(b2f_lo(uu) + b2f_lo(vv), 0.f);
            float hi = fmaxf(b2f_hi(uu) + b2f_hi(vv), 0.f);
            *(unsigned*)(t1b + (it * 8 + eg) * 72 + j * 2) =
                ((unsigned)f2b(hi) << 16) | (unsigned)f2b(lo);
        }
    }
    __syncthreads();
    const int w = tid >> 6, lane = tid & 63;
    const int t = lane & 15, quad = lane >> 4;
    f32x4 acc[4];
#pragma unroll
    for (int g = 0; g < 4; ++g) acc[g] = (f32x4){0.f, 0.f, 0.f, 0.f};
#pragma unroll
    for (int kc = 0; kc < 2; ++kc) {
        bf16x8 a = *(const bf16x8*)(t1b + (w * 16 + t) * 72 + kc * 32 + quad * 8);
#pragma unroll
        for (int g = 0; g < 4; ++g) {
            bf16x8 b = *(const bf16x8*)(wbs + (g * 16 + t) * 72 + kc * 32 + quad * 8);
            acc[g] = __builtin_amdgcn_mfma_f32_16x16x32_bf16(a, b, acc[g], 0, 0, 0);
        }
    }
    float wcv[4], bbv[4];
#pragma unroll
    for (int g = 0; g < 4; ++g) {
        wcv[g] = Wc[g * 16 + t];
        bbv[g] = bb[g * 16 + t];
    }
    const float bcv = bc[0];
#pragma unroll
    for (int r = 0; r < 4; ++r) {
        int el = w * 16 + quad * 4 + r;
        float part = 0.f;
#pragma unroll
        for (int g = 0; g < 4; ++g) {
            float t1v = b2f_s(t1b[el * 72 + g * 16 + t]);
            float t2 = fmaxf(acc[g][r] + bbv[g] + t1v, 0.f);
            part += t2 * wcv[g];
        }
        part += __shfl_xor(part, 1, 64);
        part += __shfl_xor(part, 2, 64);
        part += __shfl_xor(part, 4, 64);
        part += __shfl_xor(part, 8, 64);
        int e = eBase + el;
        if (t == 0 && e < E) out[e] = part + bcv;
    }
}

extern "C" void kernel_launch(void* const* d_in, const int* in_sizes, int n_in,
                              void* d_out, int out_size, void* d_ws,
                              size_t ws_size, hipStream_t stream) {
    const float* x = (const float*)d_in[0];
    const int* ei = (const int*)d_in[1];
    const float* W0 = (const float*)d_in[2];
    const float* W1 = (const float*)d_in[3];
    const float* W2 = (const float*)d_in[4];
    const float* W3 = (const float*)d_in[5];
    const float* a_src = (const float*)d_in[6];
    const float* a_dst = (const float*)d_in[7];
    const float* gat_b = (const float*)d_in[8];
    const float* res_W = (const float*)d_in[9];
    const float* res_b = (const float*)d_in[10];
    const float* lin_W0 = (const float*)d_in[11];
    const float* lin_b0 = (const float*)d_in[12];
    const float* lin_W1 = (const float*)d_in[13];
    const float* lin_b1 = (const float*)d_in[14];
    const float* lin_W2 = (const float*)d_in[15];
    const float* lin_b2 = (const float*)d_in[16];
    float* out = (float*)d_out;

    const int N = in_sizes[0] / 128;  // 20000
    const int E = in_sizes[1] / 2;    // 320000
    const int Etot = E + N;

    float* ws = (float*)d_ws;
    uint2* Hq = (uint2*)ws;                            // N*64 uint2
    float* feat = (float*)(Hq + (size_t)N * 64);       // N*64 f32
    float* res = feat + (size_t)N * 64;                // N*64 f32
    short* xb = (short*)(res + (size_t)N * 64);        // N*128 bf16
    short* featb = xb;                                 // alias (N*64 bf16)
    float* Ssrc = (float*)(xb + (size_t)N * 128);      // N*4
    float* Sdst = Ssrc + (size_t)N * 4;                // N*4
    short* Wt0 = (short*)(Sdst + (size_t)N * 4);       // 256*128
    short* Wt1 = Wt0 + 256 * 128;                      // 256*64
    short* Wt2 = Wt1 + 256 * 64;
    short* Wt3 = Wt2 + 256 * 64;
    short* WtR = Wt3 + 256 * 64;                       // 64*128
    short* WtU = WtR + 64 * 128;                       // 64*64
    short* WtV = WtU + 64 * 64;                        // 64*64
    short* WbT = WtV + 64 * 64;                        // 64*64
    int* deg = (int*)(WbT + 64 * 64);                  // N
    int* rowstart = deg + N;                           // N+1
    int* cursor = rowstart + N + 1;                    // N
    int* csr = cursor + N;                             // Etot
    short* Ub = (short*)Hq;                            // alias, N*64 bf16
    short* Vb = Ub + (size_t)N * 64;                   // alias, N*64 bf16

    const int gemmBlocks = (N + 63) / 64;
    const int edgeBlocks = (Etot + 255) / 256;
    const int nodeW = (N + 3) / 4;
    const short* Wts[4] = {Wt0, Wt1, Wt2, Wt3};

    // CSR build
    hipMemsetAsync(deg, 0, (size_t)N * sizeof(int), stream);
    hist_deg<<<edgeBlocks, 256, 0, stream>>>(ei, deg, E, N);
    scan_deg<<<1, 256, 0, stream>>>(deg, rowstart, cursor, N);
    fill_csr<<<edgeBlocks, 256, 0, stream>>>(ei, cursor, csr, E, N);

    // weight prep + x conversion
    prep_weights<<<8, 256, 0, stream>>>(W0, W1, W2, W3, res_W, lin_W0, lin_W1,
                                        Wt0, Wt1, Wt2, Wt3, WtR, WtU, WtV, WbT);
    convert_x<<<(N * 128 / 4 + 255) / 256, 256, 0, stream>>>(x, xb, N * 128);

    for (int i = 0; i < 4; ++i) {
        if (i == 0)
            mfma_gemm<128, 16, 1><<<gemmBlocks, 256, 0, stream>>>(
                xb, Wt0, nullptr, Hq, a_src, a_dst, Ssrc, Sdst, nullptr,
                nullptr, N);
        else
            mfma_gemm<64, 16, 1><<<gemmBlocks, 256, 0, stream>>>(
                featb, Wts[i], nullptr, Hq, a_src + i * 256, a_dst + i * 256,
                Ssrc, Sdst, nullptr, nullptr, N);
        if (i == 0)  // residual projection (reads xb; precedes gather's featb write)
            mfma_gemm<128, 4, 0><<<gemmBlocks, 256, 0, stream>>>(
                xb, WtR, res_b, nullptr, nullptr, nullptr, nullptr, nullptr,
                res, nullptr, N);
        const float* resid = (i == 0) ? res : feat;
        gat_gather<<<nodeW, 256, 0, stream>>>(csr, rowstart, Ssrc, Sdst, Hq,
                                              gat_b + i * 64, resid, feat,
                                              featb, N);
    }

    // edge classifier heads (bf16 outputs): U = feat@W0_top + b0, V = feat@W0_bot
    mfma_gemm<64, 4, 2><<<gemmBlocks, 256, 0, stream>>>(
        featb, WtU, lin_b0, nullptr, nullptr, nullptr, nullptr, nullptr,
        nullptr, Ub, N);
    mfma_gemm<64, 4, 2><<<gemmBlocks, 256, 0, stream>>>(
        featb, WtV, nullptr, nullptr, nullptr, nullptr, nullptr, nullptr,
        nullptr, Vb, N);
    edge_mlp3<<<(E + 63) / 64, 256, 0, stream>>>(
        ei, (const unsigned*)Ub, (const unsigned*)Vb, WbT, lin_b1, lin_W2,
        lin_b2, out, E);
}

// Round 5
// 399.058 us; speedup vs baseline: 3.1799x; 1.1695x over previous
//
#include <hip/hip_runtime.h>
#include <hip/hip_bf16.h>

#define NSLOPE 0.2f

typedef short bf16x8 __attribute__((ext_vector_type(8)));
typedef float f32x4 __attribute__((ext_vector_type(4)));

__device__ __forceinline__ unsigned short f2b(float f) {
    unsigned u = __float_as_uint(f);
    unsigned r = (u + 0x7FFFu + ((u >> 16) & 1u)) >> 16;
    return (unsigned short)r;
}
__device__ __forceinline__ float b2f_lo(unsigned w) {
    return __uint_as_float(w << 16);
}
__device__ __forceinline__ float b2f_hi(unsigned w) {
    return __uint_as_float(w & 0xFFFF0000u);
}
__device__ __forceinline__ float b2f_s(short s) {
    return __uint_as_float(((unsigned)(unsigned short)s) << 16);
}

// ---------------- CSR build -------------------------------------------------

__global__ __launch_bounds__(256) void hist_deg(const int* __restrict__ ei,
                                                int* __restrict__ deg, int E,
                                                int n) {
    int t = blockIdx.x * 256 + threadIdx.x;
    int Etot = E + n;
    if (t >= Etot) return;
    int d = (t < E) ? ei[E + t] : (t - E);
    atomicAdd(&deg[d], 1);
}

// multi-block exclusive scan, stage 1: per-1024-elt block local scan + sums
__global__ __launch_bounds__(256) void scan_blk(const int* __restrict__ deg,
                                                int* __restrict__ local,
                                                int* __restrict__ bsum, int n) {
    __shared__ int sm[256];
    const int base = blockIdx.x * 1024;
    const int t = threadIdx.x;
    const int i0 = base + t * 4;
    int v0 = 0, v1 = 0, v2 = 0, v3 = 0;
    if (i0 + 3 < n) {
        int4 v = *(const int4*)(deg + i0);
        v0 = v.x; v1 = v.y; v2 = v.z; v3 = v.w;
    } else {
        if (i0 < n) v0 = deg[i0];
        if (i0 + 1 < n) v1 = deg[i0 + 1];
        if (i0 + 2 < n) v2 = deg[i0 + 2];
    }
    int s = v0 + v1 + v2 + v3;
    sm[t] = s;
    __syncthreads();
    for (int off = 1; off < 256; off <<= 1) {
        int val = (t >= off) ? sm[t - off] : 0;
        __syncthreads();
        sm[t] += val;
        __syncthreads();
    }
    int ex = sm[t] - s;
    if (t == 255) bsum[blockIdx.x] = sm[255];
    if (i0 < n) local[i0] = ex;
    if (i0 + 1 < n) local[i0 + 1] = ex + v0;
    if (i0 + 2 < n) local[i0 + 2] = ex + v0 + v1;
    if (i0 + 3 < n) local[i0 + 3] = ex + v0 + v1 + v2;
}

// stage 2: scan the (<=256) block sums
__global__ __launch_bounds__(256) void scan_top(const int* __restrict__ bsum,
                                                int* __restrict__ boff,
                                                int nb) {
    __shared__ int sm[256];
    const int t = threadIdx.x;
    int s = (t < nb) ? bsum[t] : 0;
    sm[t] = s;
    __syncthreads();
    for (int off = 1; off < 256; off <<= 1) {
        int val = (t >= off) ? sm[t - off] : 0;
        __syncthreads();
        sm[t] += val;
        __syncthreads();
    }
    if (t < nb) boff[t] = sm[t] - s;
}

// stage 3: rowstart/cursor = local + block offset; rowstart[n] = Etot
__global__ __launch_bounds__(256) void scan_add(const int* __restrict__ local,
                                                const int* __restrict__ boff,
                                                int* __restrict__ rowstart,
                                                int* __restrict__ cursor,
                                                int n, int Etot) {
    int i = blockIdx.x * 256 + threadIdx.x;
    if (i > n) return;
    if (i == n) {
        rowstart[n] = Etot;
        return;
    }
    int v = local[i] + boff[i >> 10];
    rowstart[i] = v;
    cursor[i] = v;
}

__global__ __launch_bounds__(256) void fill_csr(const int* __restrict__ ei,
                                                int* __restrict__ cursor,
                                                int* __restrict__ csr, int E,
                                                int n) {
    int t = blockIdx.x * 256 + threadIdx.x;
    int Etot = E + n;
    if (t >= Etot) return;
    int s, d;
    if (t < E) { s = ei[t]; d = ei[E + t]; } else { s = d = t - E; }
    int pos = atomicAdd(&cursor[d], 1);
    csr[pos] = s;
}

// ---------------- weight prep: fp32 [K][NC] -> bf16 [NC][K] (transposed) ----
// grid: (8 matrices, 16 slices)
__global__ __launch_bounds__(256) void prep_weights(
    const float* __restrict__ W0, const float* __restrict__ W1,
    const float* __restrict__ W2, const float* __restrict__ W3,
    const float* __restrict__ resW, const float* __restrict__ linW0,
    const float* __restrict__ linW1, short* __restrict__ Wt0,
    short* __restrict__ Wt1, short* __restrict__ Wt2, short* __restrict__ Wt3,
    short* __restrict__ WtR, short* __restrict__ WtU, short* __restrict__ WtV,
    short* __restrict__ WbT) {
    const float* src;
    short* dst;
    int K, NC, rowoff = 0;
    switch (blockIdx.x) {
        case 0: src = W0; dst = Wt0; K = 128; NC = 256; break;
        case 1: src = W1; dst = Wt1; K = 64; NC = 256; break;
        case 2: src = W2; dst = Wt2; K = 64; NC = 256; break;
        case 3: src = W3; dst = Wt3; K = 64; NC = 256; break;
        case 4: src = resW; dst = WtR; K = 128; NC = 64; break;
        case 5: src = linW0; dst = WtU; K = 64; NC = 64; break;
        case 6: src = linW0; dst = WtV; K = 64; NC = 64; rowoff = 64; break;
        default: src = linW1; dst = WbT; K = 64; NC = 64; break;
    }
    for (int idx = blockIdx.y * 256 + threadIdx.x; idx < K * NC;
         idx += 256 * 16) {
        int k = idx / NC, nn = idx - k * NC;
        dst[nn * K + k] = (short)f2b(src[(k + rowoff) * NC + nn]);
    }
}

__global__ __launch_bounds__(256) void convert_x(const float* __restrict__ x,
                                                 short* __restrict__ xb,
                                                 int total) {
    int idx = (blockIdx.x * 256 + threadIdx.x) * 4;
    if (idx >= total) return;
    float4 v = *(const float4*)(x + idx);
    ushort4 o;
    o.x = f2b(v.x); o.y = f2b(v.y); o.z = f2b(v.z); o.w = f2b(v.w);
    *(ushort4*)(xb + idx) = o;
}

// ---------------- MFMA node GEMM -------------------------------------------
// Xb: [n][K] bf16.  Wt: [NG*16][K] bf16 (transposed weights, k contiguous).
// OM=0: OutF[node][NG*16] fp32 (+bias)
// OM=1: NG=16; Hq[node][64] uint2 = (pack(h0,h1), pack(h2,h3)); fused attn
//       scores -> Ssrc/Sdst[node][4]
// OM=2: OutB[node][NG*16] bf16 (+bias)
template <int K, int NG, int OM>
__global__ __launch_bounds__(256) void mfma_gemm(
    const short* __restrict__ Xb, const short* __restrict__ Wt,
    const float* __restrict__ bias, uint2* __restrict__ Hq,
    const float* __restrict__ as_l, const float* __restrict__ ad_l,
    float* __restrict__ Ssrc, float* __restrict__ Sdst,
    float* __restrict__ OutF, short* __restrict__ OutB, int n) {
    constexpr int XSTR = K + 8;   // 16B-aligned row stride, bank-spread
    constexpr int NC = NG * 16;
    __shared__ __align__(16) short Xs[64 * XSTR];
    __shared__ __align__(16) short Ws[NC * 40];  // 32 k + 8 pad per row
    const int tid = threadIdx.x;
    const int nb = blockIdx.x * 64;
    constexpr int CH = K / 8;
    for (int idx = tid; idx < 64 * CH; idx += 256) {
        int row = idx / CH, c = idx - row * CH;
        uint4 v = make_uint4(0, 0, 0, 0);
        if (nb + row < n)
            v = *(const uint4*)(Xb + (size_t)(nb + row) * K + c * 8);
        *(uint4*)(Xs + row * XSTR + c * 8) = v;
    }
    const int wid = tid >> 6;
    const int lane = tid & 63;
    const int t = lane & 15, quad = lane >> 4;
    f32x4 acc[NG];
#pragma unroll
    for (int g = 0; g < NG; ++g) acc[g] = (f32x4){0.f, 0.f, 0.f, 0.f};
#pragma unroll 1
    for (int kc = 0; kc < K / 32; ++kc) {
        __syncthreads();
        for (int idx = tid; idx < NC * 4; idx += 256) {
            int row = idx >> 2, c = idx & 3;
            uint4 v = *(const uint4*)(Wt + (size_t)row * K + kc * 32 + c * 8);
            *(uint4*)(Ws + row * 40 + c * 8) = v;
        }
        __syncthreads();
        bf16x8 a =
            *(const bf16x8*)(Xs + (wid * 16 + t) * XSTR + kc * 32 + quad * 8);
#pragma unroll
        for (int g = 0; g < NG; ++g) {
            bf16x8 b = *(const bf16x8*)(Ws + (g * 16 + t) * 40 + quad * 8);
            acc[g] = __builtin_amdgcn_mfma_f32_16x16x32_bf16(a, b, acc[g], 0, 0, 0);
        }
    }
    // epilogue: C/D layout col = g*16 + t, row(node) = nb + wid*16 + quad*4 + r
    if (OM == 1) {
#pragma unroll
        for (int r = 0; r < 4; ++r) {
            int node = nb + wid * 16 + quad * 4 + r;
            if (node >= n) continue;
#pragma unroll
            for (int g = 0; g < 4; ++g) {
                unsigned p01 = ((unsigned)f2b(acc[g + 4][r]) << 16) |
                               (unsigned)f2b(acc[g][r]);
                unsigned p23 = ((unsigned)f2b(acc[g + 12][r]) << 16) |
                               (unsigned)f2b(acc[g + 8][r]);
                Hq[(size_t)node * 64 + g * 16 + t] = make_uint2(p01, p23);
            }
        }
        // fused attention scores
        float asv[16], adv[16];
#pragma unroll
        for (int G = 0; G < 16; ++G) {
            asv[G] = as_l[G * 16 + t];
            adv[G] = ad_l[G * 16 + t];
        }
#pragma unroll
        for (int r = 0; r < 4; ++r) {
            int node = nb + wid * 16 + quad * 4 + r;
            float pv[8];
#pragma unroll
            for (int h = 0; h < 4; ++h) {
                float ps = 0.f, pd = 0.f;
#pragma unroll
                for (int j = 0; j < 4; ++j) {
                    float a = acc[h * 4 + j][r];
                    ps += a * asv[h * 4 + j];
                    pd += a * adv[h * 4 + j];
                }
                pv[h] = ps;
                pv[4 + h] = pd;
            }
#pragma unroll
            for (int off = 1; off < 16; off <<= 1) {
#pragma unroll
                for (int i = 0; i < 8; ++i) pv[i] += __shfl_xor(pv[i], off, 64);
            }
            if (t == 0 && node < n) {
                *(float4*)&Ssrc[node * 4] =
                    make_float4(pv[0], pv[1], pv[2], pv[3]);
                *(float4*)&Sdst[node * 4] =
                    make_float4(pv[4], pv[5], pv[6], pv[7]);
            }
        }
    } else {
        float bv[NG];
#pragma unroll
        for (int g = 0; g < NG; ++g) bv[g] = bias ? bias[g * 16 + t] : 0.f;
#pragma unroll
        for (int r = 0; r < 4; ++r) {
            int node = nb + wid * 16 + quad * 4 + r;
            if (node >= n) continue;
            if (OM == 0) {
#pragma unroll
                for (int g = 0; g < NG; ++g)
                    OutF[(size_t)node * NC + g * 16 + t] = acc[g][r] + bv[g];
            } else {
#pragma unroll
                for (int g = 0; g < NG; ++g)
                    OutB[(size_t)node * NC + g * 16 + t] =
                        (short)f2b(acc[g][r] + bv[g]);
            }
        }
    }
}

// ---------------- fused GAT softmax + aggregate + epilogue (gather) ---------
__global__ __launch_bounds__(256) void gat_gather(
    const int* __restrict__ csr, const int* __restrict__ rowstart,
    const float* __restrict__ Ssrc, const float* __restrict__ Sdst,
    const uint2* __restrict__ Hq, const float* __restrict__ gb,
    const float* __restrict__ resid, float* __restrict__ featOut,
    short* __restrict__ featB, int n) {
    const int wid = threadIdx.x >> 6;
    const int lane = threadIdx.x & 63;
    const int node = blockIdx.x * 4 + wid;
    if (node >= n) return;
    const int start = rowstart[node];
    const int end = rowstart[node + 1];
    const float4 sd = *(const float4*)&Sdst[node * 4];

    // pass 1: per-head max (lane = el*4 + h)
    const int el = lane >> 2;
    const int h = lane & 3;
    const float sdh = (h == 0) ? sd.x : (h == 1) ? sd.y : (h == 2) ? sd.z : sd.w;
    float mval = -1e30f;
    for (int b = start; b < end; b += 16) {
        int e = b + el;
        if (e < end) {
            int s = csr[e];
            float sc = Ssrc[s * 4 + h] + sdh;
            sc = sc > 0.f ? sc : NSLOPE * sc;
            mval = fmaxf(mval, sc);
        }
    }
#pragma unroll
    for (int off = 4; off < 64; off <<= 1)
        mval = fmaxf(mval, __shfl_xor(mval, off, 64));
    const float m0 = __shfl(mval, 0, 64);
    const float m1 = __shfl(mval, 1, 64);
    const float m2 = __shfl(mval, 2, 64);
    const float m3 = __shfl(mval, 3, 64);

    // pass 2: lane = channel
    float u0 = 0.f, u1 = 0.f, u2 = 0.f, u3 = 0.f;
    float z0 = 0.f, z1 = 0.f, z2 = 0.f, z3 = 0.f;
#pragma unroll 4
    for (int e = start; e < end; ++e) {
        int s = csr[e];
        float4 ss = *(const float4*)&Ssrc[s * 4];
        float c0 = ss.x + sd.x, c1 = ss.y + sd.y, c2 = ss.z + sd.z,
              c3 = ss.w + sd.w;
        c0 = c0 > 0.f ? c0 : NSLOPE * c0;
        c1 = c1 > 0.f ? c1 : NSLOPE * c1;
        c2 = c2 > 0.f ? c2 : NSLOPE * c2;
        c3 = c3 > 0.f ? c3 : NSLOPE * c3;
        float p0 = __expf(c0 - m0), p1 = __expf(c1 - m1);
        float p2 = __expf(c2 - m2), p3 = __expf(c3 - m3);
        uint2 hv = Hq[(size_t)s * 64 + lane];
        u0 += p0 * b2f_lo(hv.x);
        u1 += p1 * b2f_hi(hv.x);
        u2 += p2 * b2f_lo(hv.y);
        u3 += p3 * b2f_hi(hv.y);
        z0 += p0; z1 += p1; z2 += p2; z3 += p3;
    }
    float val = 0.25f * (u0 / z0 + u1 / z1 + u2 / z2 + u3 / z3) + gb[lane] +
                resid[(size_t)node * 64 + lane];
    val = val > 0.f ? val : expm1f(val);
    featOut[(size_t)node * 64 + lane] = val;
    featB[(size_t)node * 64 + lane] = (short)f2b(val);
}

// ---------------- edge classifier (MFMA) ------------------------------------
// t1 = relu(U[row]+V[col]) (bf16 in), t2 = relu(t1@Wb + bb + t1), out = t2@Wc+bc
__global__ __launch_bounds__(256) void edge_mlp3(
    const int* __restrict__ ei, const unsigned* __restrict__ Ub,
    const unsigned* __restrict__ Vb, const short* __restrict__ WbT,
    const float* __restrict__ bb, const float* __restrict__ Wc,
    const float* __restrict__ bc, float* __restrict__ out, int E) {
    __shared__ __align__(16) short t1b[64 * 72];
    __shared__ __align__(16) short wbs[64 * 72];
    const int tid = threadIdx.x;
    const int eBase = blockIdx.x * 64;
    // stage WbT (64x64 bf16) into LDS
    for (int idx = tid; idx < 512; idx += 256) {
        int row = idx >> 3, c = idx & 7;
        *(uint4*)(wbs + row * 72 + c * 8) =
            *(const uint4*)(WbT + row * 64 + c * 8);
    }
    // stage t1 = relu(U[r]+V[c]) bf16; hoist all index loads first
    {
        const int j = tid & 31;   // channel pair
        const int eg = tid >> 5;  // 8 edge groups
        int rr[8], cc[8];
#pragma unroll
        for (int it = 0; it < 8; ++it) {
            int e = eBase + it * 8 + eg;
            rr[it] = (e < E) ? ei[e] : 0;
            cc[it] = (e < E) ? ei[E + e] : 0;
        }
#pragma unroll
        for (int it = 0; it < 8; ++it) {
            unsigned uu = Ub[(size_t)rr[it] * 32 + j];
            unsigned vv = Vb[(size_t)cc[it] * 32 + j];
            float lo = fmaxf(b2f_lo(uu) + b2f_lo(vv), 0.f);
            float hi = fmaxf(b2f_hi(uu) + b2f_hi(vv), 0.f);
            *(unsigned*)(t1b + (it * 8 + eg) * 72 + j * 2) =
                ((unsigned)f2b(hi) << 16) | (unsigned)f2b(lo);
        }
    }
    __syncthreads();
    const int w = tid >> 6, lane = tid & 63;
    const int t = lane & 15, quad = lane >> 4;
    f32x4 acc[4];
#pragma unroll
    for (int g = 0; g < 4; ++g) acc[g] = (f32x4){0.f, 0.f, 0.f, 0.f};
#pragma unroll
    for (int kc = 0; kc < 2; ++kc) {
        bf16x8 a = *(const bf16x8*)(t1b + (w * 16 + t) * 72 + kc * 32 + quad * 8);
#pragma unroll
        for (int g = 0; g < 4; ++g) {
            bf16x8 b = *(const bf16x8*)(wbs + (g * 16 + t) * 72 + kc * 32 + quad * 8);
            acc[g] = __builtin_amdgcn_mfma_f32_16x16x32_bf16(a, b, acc[g], 0, 0, 0);
        }
    }
    float wcv[4], bbv[4];
#pragma unroll
    for (int g = 0; g < 4; ++g) {
        wcv[g] = Wc[g * 16 + t];
        bbv[g] = bb[g * 16 + t];
    }
    const float bcv = bc[0];
#pragma unroll
    for (int r = 0; r < 4; ++r) {
        int el = w * 16 + quad * 4 + r;
        float part = 0.f;
#pragma unroll
        for (int g = 0; g < 4; ++g) {
            float t1v = b2f_s(t1b[el * 72 + g * 16 + t]);
            float t2 = fmaxf(acc[g][r] + bbv[g] + t1v, 0.f);
            part += t2 * wcv[g];
        }
        part += __shfl_xor(part, 1, 64);
        part += __shfl_xor(part, 2, 64);
        part += __shfl_xor(part, 4, 64);
        part += __shfl_xor(part, 8, 64);
        int e = eBase + el;
        if (t == 0 && e < E) out[e] = part + bcv;
    }
}

extern "C" void kernel_launch(void* const* d_in, const int* in_sizes, int n_in,
                              void* d_out, int out_size, void* d_ws,
                              size_t ws_size, hipStream_t stream) {
    const float* x = (const float*)d_in[0];
    const int* ei = (const int*)d_in[1];
    const float* W0 = (const float*)d_in[2];
    const float* W1 = (const float*)d_in[3];
    const float* W2 = (const float*)d_in[4];
    const float* W3 = (const float*)d_in[5];
    const float* a_src = (const float*)d_in[6];
    const float* a_dst = (const float*)d_in[7];
    const float* gat_b = (const float*)d_in[8];
    const float* res_W = (const float*)d_in[9];
    const float* res_b = (const float*)d_in[10];
    const float* lin_W0 = (const float*)d_in[11];
    const float* lin_b0 = (const float*)d_in[12];
    const float* lin_W1 = (const float*)d_in[13];
    const float* lin_b1 = (const float*)d_in[14];
    const float* lin_W2 = (const float*)d_in[15];
    const float* lin_b2 = (const float*)d_in[16];
    float* out = (float*)d_out;

    const int N = in_sizes[0] / 128;  // 20000
    const int E = in_sizes[1] / 2;    // 320000
    const int Etot = E + N;

    float* ws = (float*)d_ws;
    uint2* Hq = (uint2*)ws;                            // N*64 uint2
    float* feat = (float*)(Hq + (size_t)N * 64);       // N*64 f32
    float* res = feat + (size_t)N * 64;                // N*64 f32
    short* xb = (short*)(res + (size_t)N * 64);        // N*128 bf16
    short* featb = xb;                                 // alias (N*64 bf16)
    float* Ssrc = (float*)(xb + (size_t)N * 128);      // N*4
    float* Sdst = Ssrc + (size_t)N * 4;                // N*4
    short* Wt0 = (short*)(Sdst + (size_t)N * 4);       // 256*128
    short* Wt1 = Wt0 + 256 * 128;                      // 256*64
    short* Wt2 = Wt1 + 256 * 64;
    short* Wt3 = Wt2 + 256 * 64;
    short* WtR = Wt3 + 256 * 64;                       // 64*128
    short* WtU = WtR + 64 * 128;                       // 64*64
    short* WtV = WtU + 64 * 64;                        // 64*64
    short* WbT = WtV + 64 * 64;                        // 64*64
    int* deg = (int*)(WbT + 64 * 64);                  // N
    int* rowstart = deg + N;                           // N+1
    int* cursor = rowstart + N + 1;                    // N
    int* csr = cursor + N;                             // Etot
    int* locals = csr + Etot;                          // N
    int* bsum = locals + N;                            // 256
    int* boff = bsum + 256;                            // 256
    short* Ub = (short*)Hq;                            // alias, N*64 bf16
    short* Vb = Ub + (size_t)N * 64;                   // alias, N*64 bf16

    const int gemmBlocks = (N + 63) / 64;
    const int edgeBlocks = (Etot + 255) / 256;
    const int nodeW = (N + 3) / 4;
    const int scanBlocks = (N + 1023) / 1024;
    const short* Wts[4] = {Wt0, Wt1, Wt2, Wt3};

    // CSR build (parallel scan)
    hipMemsetAsync(deg, 0, (size_t)N * sizeof(int), stream);
    hist_deg<<<edgeBlocks, 256, 0, stream>>>(ei, deg, E, N);
    scan_blk<<<scanBlocks, 256, 0, stream>>>(deg, locals, bsum, N);
    scan_top<<<1, 256, 0, stream>>>(bsum, boff, scanBlocks);
    scan_add<<<(N + 256) / 256, 256, 0, stream>>>(locals, boff, rowstart,
                                                  cursor, N, Etot);
    fill_csr<<<edgeBlocks, 256, 0, stream>>>(ei, cursor, csr, E, N);

    // weight prep + x conversion
    prep_weights<<<dim3(8, 16), 256, 0, stream>>>(W0, W1, W2, W3, res_W,
                                                  lin_W0, lin_W1, Wt0, Wt1,
                                                  Wt2, Wt3, WtR, WtU, WtV, WbT);
    convert_x<<<(N * 128 / 4 + 255) / 256, 256, 0, stream>>>(x, xb, N * 128);

    for (int i = 0; i < 4; ++i) {
        if (i == 0)
            mfma_gemm<128, 16, 1><<<gemmBlocks, 256, 0, stream>>>(
                xb, Wt0, nullptr, Hq, a_src, a_dst, Ssrc, Sdst, nullptr,
                nullptr, N);
        else
            mfma_gemm<64, 16, 1><<<gemmBlocks, 256, 0, stream>>>(
                featb, Wts[i], nullptr, Hq, a_src + i * 256, a_dst + i * 256,
                Ssrc, Sdst, nullptr, nullptr, N);
        if (i == 0)  // residual projection (reads xb; precedes gather's featb write)
            mfma_gemm<128, 4, 0><<<gemmBlocks, 256, 0, stream>>>(
                xb, WtR, res_b, nullptr, nullptr, nullptr, nullptr, nullptr,
                res, nullptr, N);
        const float* resid = (i == 0) ? res : feat;
        gat_gather<<<nodeW, 256, 0, stream>>>(csr, rowstart, Ssrc, Sdst, Hq,
                                              gat_b + i * 64, resid, feat,
                                              featb, N);
    }

    // edge classifier heads (bf16 outputs): U = feat@W0_top + b0, V = feat@W0_bot
    mfma_gemm<64, 4, 2><<<gemmBlocks, 256, 0, stream>>>(
        featb, WtU, lin_b0, nullptr, nullptr, nullptr, nullptr, nullptr,
        nullptr, Ub, N);
    mfma_gemm<64, 4, 2><<<gemmBlocks, 256, 0, stream>>>(
        featb, WtV, nullptr, nullptr, nullptr, nullptr, nullptr, nullptr,
        nullptr, Vb, N);
    edge_mlp3<<<(E + 63) / 64, 256, 0, stream>>>(
        ei, (const unsigned*)Ub, (const unsigned*)Vb, WbT, lin_b1, lin_W2,
        lin_b2, out, E);
}

// Round 6
// 356.998 us; speedup vs baseline: 3.5545x; 1.1178x over previous
//
#include <hip/hip_runtime.h>
#include <hip/hip_bf16.h>

#define NSLOPE 0.2f

typedef short bf16x8 __attribute__((ext_vector_type(8)));
typedef float f32x4 __attribute__((ext_vector_type(4)));

__device__ __forceinline__ unsigned short f2b(float f) {
    unsigned u = __float_as_uint(f);
    unsigned r = (u + 0x7FFFu + ((u >> 16) & 1u)) >> 16;
    return (unsigned short)r;
}
__device__ __forceinline__ float b2f_lo(unsigned w) {
    return __uint_as_float(w << 16);
}
__device__ __forceinline__ float b2f_hi(unsigned w) {
    return __uint_as_float(w & 0xFFFF0000u);
}
__device__ __forceinline__ float b2f_s(short s) {
    return __uint_as_float(((unsigned)(unsigned short)s) << 16);
}

// ---------------- CSR build -------------------------------------------------

__global__ __launch_bounds__(256) void hist_deg(const int* __restrict__ ei,
                                                int* __restrict__ deg, int E,
                                                int n) {
    int t = blockIdx.x * 256 + threadIdx.x;
    int Etot = E + n;
    if (t >= Etot) return;
    int d = (t < E) ? ei[E + t] : (t - E);
    atomicAdd(&deg[d], 1);
}

__global__ __launch_bounds__(256) void scan_blk(const int* __restrict__ deg,
                                                int* __restrict__ local,
                                                int* __restrict__ bsum, int n) {
    __shared__ int sm[256];
    const int base = blockIdx.x * 1024;
    const int t = threadIdx.x;
    const int i0 = base + t * 4;
    int v0 = 0, v1 = 0, v2 = 0, v3 = 0;
    if (i0 + 3 < n) {
        int4 v = *(const int4*)(deg + i0);
        v0 = v.x; v1 = v.y; v2 = v.z; v3 = v.w;
    } else {
        if (i0 < n) v0 = deg[i0];
        if (i0 + 1 < n) v1 = deg[i0 + 1];
        if (i0 + 2 < n) v2 = deg[i0 + 2];
    }
    int s = v0 + v1 + v2 + v3;
    sm[t] = s;
    __syncthreads();
    for (int off = 1; off < 256; off <<= 1) {
        int val = (t >= off) ? sm[t - off] : 0;
        __syncthreads();
        sm[t] += val;
        __syncthreads();
    }
    int ex = sm[t] - s;
    if (t == 255) bsum[blockIdx.x] = sm[255];
    if (i0 < n) local[i0] = ex;
    if (i0 + 1 < n) local[i0 + 1] = ex + v0;
    if (i0 + 2 < n) local[i0 + 2] = ex + v0 + v1;
    if (i0 + 3 < n) local[i0 + 3] = ex + v0 + v1 + v2;
}

__global__ __launch_bounds__(256) void scan_top(const int* __restrict__ bsum,
                                                int* __restrict__ boff,
                                                int nb) {
    __shared__ int sm[256];
    const int t = threadIdx.x;
    int s = (t < nb) ? bsum[t] : 0;
    sm[t] = s;
    __syncthreads();
    for (int off = 1; off < 256; off <<= 1) {
        int val = (t >= off) ? sm[t - off] : 0;
        __syncthreads();
        sm[t] += val;
        __syncthreads();
    }
    if (t < nb) boff[t] = sm[t] - s;
}

__global__ __launch_bounds__(256) void scan_add(const int* __restrict__ local,
                                                const int* __restrict__ boff,
                                                int* __restrict__ rowstart,
                                                int* __restrict__ cursor,
                                                int n, int Etot) {
    int i = blockIdx.x * 256 + threadIdx.x;
    if (i > n) return;
    if (i == n) {
        rowstart[n] = Etot;
        return;
    }
    int v = local[i] + boff[i >> 10];
    rowstart[i] = v;
    cursor[i] = v;
}

__global__ __launch_bounds__(256) void fill_csr(const int* __restrict__ ei,
                                                int* __restrict__ cursor,
                                                int* __restrict__ csr, int E,
                                                int n) {
    int t = blockIdx.x * 256 + threadIdx.x;
    int Etot = E + n;
    if (t >= Etot) return;
    int s, d;
    if (t < E) { s = ei[t]; d = ei[E + t]; } else { s = d = t - E; }
    int pos = atomicAdd(&cursor[d], 1);
    csr[pos] = s;
}

// ---------------- weight prep: fp32 [K][NC] -> bf16 [NC][K] (transposed) ----
__global__ __launch_bounds__(256) void prep_weights(
    const float* __restrict__ W0, const float* __restrict__ W1,
    const float* __restrict__ W2, const float* __restrict__ W3,
    const float* __restrict__ resW, const float* __restrict__ linW0,
    const float* __restrict__ linW1, short* __restrict__ Wt0,
    short* __restrict__ Wt1, short* __restrict__ Wt2, short* __restrict__ Wt3,
    short* __restrict__ WtR, short* __restrict__ WtU, short* __restrict__ WtV,
    short* __restrict__ WbT) {
    const float* src;
    short* dst;
    int K, NC, rowoff = 0;
    switch (blockIdx.x) {
        case 0: src = W0; dst = Wt0; K = 128; NC = 256; break;
        case 1: src = W1; dst = Wt1; K = 64; NC = 256; break;
        case 2: src = W2; dst = Wt2; K = 64; NC = 256; break;
        case 3: src = W3; dst = Wt3; K = 64; NC = 256; break;
        case 4: src = resW; dst = WtR; K = 128; NC = 64; break;
        case 5: src = linW0; dst = WtU; K = 64; NC = 64; break;
        case 6: src = linW0; dst = WtV; K = 64; NC = 64; rowoff = 64; break;
        default: src = linW1; dst = WbT; K = 64; NC = 64; break;
    }
    for (int idx = blockIdx.y * 256 + threadIdx.x; idx < K * NC;
         idx += 256 * 16) {
        int k = idx / NC, nn = idx - k * NC;
        dst[nn * K + k] = (short)f2b(src[(k + rowoff) * NC + nn]);
    }
}

__global__ __launch_bounds__(128) void bias_prep(const float* __restrict__ b0,
                                                 float* __restrict__ b128) {
    int i = threadIdx.x;
    b128[i] = (i < 64) ? b0[i] : 0.f;
}

__global__ __launch_bounds__(256) void convert_x(const float* __restrict__ x,
                                                 short* __restrict__ xb,
                                                 int total) {
    int idx = (blockIdx.x * 256 + threadIdx.x) * 4;
    if (idx >= total) return;
    float4 v = *(const float4*)(x + idx);
    ushort4 o;
    o.x = f2b(v.x); o.y = f2b(v.y); o.z = f2b(v.z); o.w = f2b(v.w);
    *(ushort4*)(xb + idx) = o;
}

// ---------------- MFMA node GEMM -------------------------------------------
// OM=0: OutF fp32 (+bias); OM=1: Hq pack + fused attn scores; OM=2: OutB bf16
template <int K, int NG, int OM>
__global__ __launch_bounds__(256) void mfma_gemm(
    const short* __restrict__ Xb, const short* __restrict__ Wt,
    const float* __restrict__ bias, uint2* __restrict__ Hq,
    const float* __restrict__ as_l, const float* __restrict__ ad_l,
    float* __restrict__ Ssrc, float* __restrict__ Sdst,
    float* __restrict__ OutF, short* __restrict__ OutB, int n) {
    constexpr int XSTR = K + 8;
    constexpr int NC = NG * 16;
    __shared__ __align__(16) short Xs[64 * XSTR];
    __shared__ __align__(16) short Ws[NC * 40];
    const int tid = threadIdx.x;
    const int nb = blockIdx.x * 64;
    constexpr int CH = K / 8;
    for (int idx = tid; idx < 64 * CH; idx += 256) {
        int row = idx / CH, c = idx - row * CH;
        uint4 v = make_uint4(0, 0, 0, 0);
        if (nb + row < n)
            v = *(const uint4*)(Xb + (size_t)(nb + row) * K + c * 8);
        *(uint4*)(Xs + row * XSTR + c * 8) = v;
    }
    const int wid = tid >> 6;
    const int lane = tid & 63;
    const int t = lane & 15, quad = lane >> 4;
    f32x4 acc[NG];
#pragma unroll
    for (int g = 0; g < NG; ++g) acc[g] = (f32x4){0.f, 0.f, 0.f, 0.f};
#pragma unroll 1
    for (int kc = 0; kc < K / 32; ++kc) {
        __syncthreads();
        for (int idx = tid; idx < NC * 4; idx += 256) {
            int row = idx >> 2, c = idx & 3;
            uint4 v = *(const uint4*)(Wt + (size_t)row * K + kc * 32 + c * 8);
            *(uint4*)(Ws + row * 40 + c * 8) = v;
        }
        __syncthreads();
        bf16x8 a =
            *(const bf16x8*)(Xs + (wid * 16 + t) * XSTR + kc * 32 + quad * 8);
#pragma unroll
        for (int g = 0; g < NG; ++g) {
            bf16x8 b = *(const bf16x8*)(Ws + (g * 16 + t) * 40 + quad * 8);
            acc[g] = __builtin_amdgcn_mfma_f32_16x16x32_bf16(a, b, acc[g], 0, 0, 0);
        }
    }
    if (OM == 1) {
#pragma unroll
        for (int r = 0; r < 4; ++r) {
            int node = nb + wid * 16 + quad * 4 + r;
            if (node >= n) continue;
#pragma unroll
            for (int g = 0; g < 4; ++g) {
                unsigned p01 = ((unsigned)f2b(acc[g + 4][r]) << 16) |
                               (unsigned)f2b(acc[g][r]);
                unsigned p23 = ((unsigned)f2b(acc[g + 12][r]) << 16) |
                               (unsigned)f2b(acc[g + 8][r]);
                Hq[(size_t)node * 64 + g * 16 + t] = make_uint2(p01, p23);
            }
        }
        float asv[16], adv[16];
#pragma unroll
        for (int G = 0; G < 16; ++G) {
            asv[G] = as_l[G * 16 + t];
            adv[G] = ad_l[G * 16 + t];
        }
#pragma unroll
        for (int r = 0; r < 4; ++r) {
            int node = nb + wid * 16 + quad * 4 + r;
            float pv[8];
#pragma unroll
            for (int h = 0; h < 4; ++h) {
                float ps = 0.f, pd = 0.f;
#pragma unroll
                for (int j = 0; j < 4; ++j) {
                    float a = acc[h * 4 + j][r];
                    ps += a * asv[h * 4 + j];
                    pd += a * adv[h * 4 + j];
                }
                pv[h] = ps;
                pv[4 + h] = pd;
            }
#pragma unroll
            for (int off = 1; off < 16; off <<= 1) {
#pragma unroll
                for (int i = 0; i < 8; ++i) pv[i] += __shfl_xor(pv[i], off, 64);
            }
            if (t == 0 && node < n) {
                *(float4*)&Ssrc[node * 4] =
                    make_float4(pv[0], pv[1], pv[2], pv[3]);
                *(float4*)&Sdst[node * 4] =
                    make_float4(pv[4], pv[5], pv[6], pv[7]);
            }
        }
    } else {
        float bv[NG];
#pragma unroll
        for (int g = 0; g < NG; ++g) bv[g] = bias ? bias[g * 16 + t] : 0.f;
#pragma unroll
        for (int r = 0; r < 4; ++r) {
            int node = nb + wid * 16 + quad * 4 + r;
            if (node >= n) continue;
            if (OM == 0) {
#pragma unroll
                for (int g = 0; g < NG; ++g)
                    OutF[(size_t)node * NC + g * 16 + t] = acc[g][r] + bv[g];
            } else {
#pragma unroll
                for (int g = 0; g < NG; ++g)
                    OutB[(size_t)node * NC + g * 16 + t] =
                        (short)f2b(acc[g][r] + bv[g]);
            }
        }
    }
}

// ---------------- fused GAT softmax + aggregate + epilogue (gather) ---------
// One wave per dst node, single pass (no max-sub: scores are O(1), exp safe).
// Batch of 16 edges: lane el*4+h computes p once; shuffle-broadcast to all.
__global__ __launch_bounds__(256) void gat_gather(
    const int* __restrict__ csr, const int* __restrict__ rowstart,
    const float* __restrict__ Ssrc, const float* __restrict__ Sdst,
    const uint2* __restrict__ Hq, const float* __restrict__ gb,
    const float* __restrict__ resid, float* __restrict__ featOut,
    short* __restrict__ featB, int n) {
    const int wid = threadIdx.x >> 6;
    const int lane = threadIdx.x & 63;
    const int node = blockIdx.x * 4 + wid;
    if (node >= n) return;
    const int start = rowstart[node];
    const int end = rowstart[node + 1];
    const int el = lane >> 2;  // edge slot 0..15
    const int h = lane & 3;    // head
    const float4 sd = *(const float4*)&Sdst[node * 4];
    const float sdh = (h == 0) ? sd.x : (h == 1) ? sd.y : (h == 2) ? sd.z : sd.w;

    float u0 = 0.f, u1 = 0.f, u2 = 0.f, u3 = 0.f, zacc = 0.f;
    for (int b = start; b < end; b += 16) {
        const int nEd = min(16, end - b);
        int s = 0;
        float p = 0.f;
        if (el < nEd) {
            s = csr[b + el];
            float sc = Ssrc[s * 4 + h] + sdh;
            sc = sc > 0.f ? sc : NSLOPE * sc;
            p = __expf(sc);
        }
        zacc += p;
        if (nEd == 16) {
#pragma unroll 4
            for (int j = 0; j < 16; ++j) {
                int sj = __shfl(s, j * 4, 64);
                float p0 = __shfl(p, j * 4 + 0, 64);
                float p1 = __shfl(p, j * 4 + 1, 64);
                float p2 = __shfl(p, j * 4 + 2, 64);
                float p3 = __shfl(p, j * 4 + 3, 64);
                uint2 hv = Hq[(size_t)sj * 64 + lane];
                u0 += p0 * b2f_lo(hv.x);
                u1 += p1 * b2f_hi(hv.x);
                u2 += p2 * b2f_lo(hv.y);
                u3 += p3 * b2f_hi(hv.y);
            }
        } else {
#pragma unroll 4
            for (int j = 0; j < nEd; ++j) {
                int sj = __shfl(s, j * 4, 64);
                float p0 = __shfl(p, j * 4 + 0, 64);
                float p1 = __shfl(p, j * 4 + 1, 64);
                float p2 = __shfl(p, j * 4 + 2, 64);
                float p3 = __shfl(p, j * 4 + 3, 64);
                uint2 hv = Hq[(size_t)sj * 64 + lane];
                u0 += p0 * b2f_lo(hv.x);
                u1 += p1 * b2f_hi(hv.x);
                u2 += p2 * b2f_lo(hv.y);
                u3 += p3 * b2f_hi(hv.y);
            }
        }
    }
    // z: reduce over the 16 edge slots (stride-4 lanes share a head)
#pragma unroll
    for (int off = 4; off < 64; off <<= 1) zacc += __shfl_xor(zacc, off, 64);
    const float z0 = __shfl(zacc, 0, 64);
    const float z1 = __shfl(zacc, 1, 64);
    const float z2 = __shfl(zacc, 2, 64);
    const float z3 = __shfl(zacc, 3, 64);
    float val = 0.25f * (u0 / z0 + u1 / z1 + u2 / z2 + u3 / z3) + gb[lane] +
                resid[(size_t)node * 64 + lane];
    val = val > 0.f ? val : expm1f(val);
    featOut[(size_t)node * 64 + lane] = val;
    featB[(size_t)node * 64 + lane] = (short)f2b(val);
}

// ---------------- edge classifier (MFMA) ------------------------------------
// UV: [node][128] bf16 (U cols 0..63 incl b0, V cols 64..127)
__global__ __launch_bounds__(256) void edge_mlp3(
    const int* __restrict__ ei, const unsigned* __restrict__ UV,
    const short* __restrict__ WbT, const float* __restrict__ bb,
    const float* __restrict__ Wc, const float* __restrict__ bc,
    float* __restrict__ out, int E) {
    __shared__ __align__(16) short t1b[64 * 72];
    __shared__ __align__(16) short wbs[64 * 72];
    const int tid = threadIdx.x;
    const int eBase = blockIdx.x * 64;
    for (int idx = tid; idx < 512; idx += 256) {
        int row = idx >> 3, c = idx & 7;
        *(uint4*)(wbs + row * 72 + c * 8) =
            *(const uint4*)(WbT + row * 64 + c * 8);
    }
    {
        const int j = tid & 31;   // channel pair
        const int eg = tid >> 5;  // 8 edge groups
        int rr[8], cc[8];
#pragma unroll
        for (int it = 0; it < 8; ++it) {
            int e = eBase + it * 8 + eg;
            rr[it] = (e < E) ? ei[e] : 0;
            cc[it] = (e < E) ? ei[E + e] : 0;
        }
#pragma unroll
        for (int it = 0; it < 8; ++it) {
            unsigned uu = UV[(size_t)rr[it] * 64 + j];
            unsigned vv = UV[(size_t)cc[it] * 64 + 32 + j];
            float lo = fmaxf(b2f_lo(uu) + b2f_lo(vv), 0.f);
            float hi = fmaxf(b2f_hi(uu) + b2f_hi(vv), 0.f);
            *(unsigned*)(t1b + (it * 8 + eg) * 72 + j * 2) =
                ((unsigned)f2b(hi) << 16) | (unsigned)f2b(lo);
        }
    }
    __syncthreads();
    const int w = tid >> 6, lane = tid & 63;
    const int t = lane & 15, quad = lane >> 4;
    f32x4 acc[4];
#pragma unroll
    for (int g = 0; g < 4; ++g) acc[g] = (f32x4){0.f, 0.f, 0.f, 0.f};
#pragma unroll
    for (int kc = 0; kc < 2; ++kc) {
        bf16x8 a = *(const bf16x8*)(t1b + (w * 16 + t) * 72 + kc * 32 + quad * 8);
#pragma unroll
        for (int g = 0; g < 4; ++g) {
            bf16x8 b = *(const bf16x8*)(wbs + (g * 16 + t) * 72 + kc * 32 + quad * 8);
            acc[g] = __builtin_amdgcn_mfma_f32_16x16x32_bf16(a, b, acc[g], 0, 0, 0);
        }
    }
    float wcv[4], bbv[4];
#pragma unroll
    for (int g = 0; g < 4; ++g) {
        wcv[g] = Wc[g * 16 + t];
        bbv[g] = bb[g * 16 + t];
    }
    const float bcv = bc[0];
#pragma unroll
    for (int r = 0; r < 4; ++r) {
        int el = w * 16 + quad * 4 + r;
        float part = 0.f;
#pragma unroll
        for (int g = 0; g < 4; ++g) {
            float t1v = b2f_s(t1b[el * 72 + g * 16 + t]);
            float t2 = fmaxf(acc[g][r] + bbv[g] + t1v, 0.f);
            part += t2 * wcv[g];
        }
        part += __shfl_xor(part, 1, 64);
        part += __shfl_xor(part, 2, 64);
        part += __shfl_xor(part, 4, 64);
        part += __shfl_xor(part, 8, 64);
        int e = eBase + el;
        if (t == 0 && e < E) out[e] = part + bcv;
    }
}

extern "C" void kernel_launch(void* const* d_in, const int* in_sizes, int n_in,
                              void* d_out, int out_size, void* d_ws,
                              size_t ws_size, hipStream_t stream) {
    const float* x = (const float*)d_in[0];
    const int* ei = (const int*)d_in[1];
    const float* W0 = (const float*)d_in[2];
    const float* W1 = (const float*)d_in[3];
    const float* W2 = (const float*)d_in[4];
    const float* W3 = (const float*)d_in[5];
    const float* a_src = (const float*)d_in[6];
    const float* a_dst = (const float*)d_in[7];
    const float* gat_b = (const float*)d_in[8];
    const float* res_W = (const float*)d_in[9];
    const float* res_b = (const float*)d_in[10];
    const float* lin_W0 = (const float*)d_in[11];
    const float* lin_b0 = (const float*)d_in[12];
    const float* lin_W1 = (const float*)d_in[13];
    const float* lin_b1 = (const float*)d_in[14];
    const float* lin_W2 = (const float*)d_in[15];
    const float* lin_b2 = (const float*)d_in[16];
    float* out = (float*)d_out;

    const int N = in_sizes[0] / 128;  // 20000
    const int E = in_sizes[1] / 2;    // 320000
    const int Etot = E + N;

    float* ws = (float*)d_ws;
    uint2* Hq = (uint2*)ws;                            // N*64 uint2
    float* feat = (float*)(Hq + (size_t)N * 64);       // N*64 f32
    float* res = feat + (size_t)N * 64;                // N*64 f32
    short* xb = (short*)(res + (size_t)N * 64);        // N*128 bf16
    short* featb = xb;                                 // alias (N*64 bf16)
    float* Ssrc = (float*)(xb + (size_t)N * 128);      // N*4
    float* Sdst = Ssrc + (size_t)N * 4;                // N*4
    short* Wt0 = (short*)(Sdst + (size_t)N * 4);       // 256*128
    short* Wt1 = Wt0 + 256 * 128;                      // 256*64
    short* Wt2 = Wt1 + 256 * 64;
    short* Wt3 = Wt2 + 256 * 64;
    short* WtR = Wt3 + 256 * 64;                       // 64*128
    short* WtU = WtR + 64 * 128;                       // 64*64 (U cols)
    short* WtV = WtU + 64 * 64;                        // 64*64 (V cols, contig)
    short* WbT = WtV + 64 * 64;                        // 64*64
    int* deg = (int*)(WbT + 64 * 64);                  // N
    int* rowstart = deg + N;                           // N+1
    int* cursor = rowstart + N + 1;                    // N
    int* csr = cursor + N;                             // Etot
    int* locals = csr + Etot;                          // N
    int* bsum = locals + N;                            // 256
    int* boff = bsum + 256;                            // 256
    float* bias128 = (float*)(boff + 256);             // 128
    short* UVb = (short*)Hq;                           // alias, N*128 bf16

    const int gemmBlocks = (N + 63) / 64;
    const int edgeBlocks = (Etot + 255) / 256;
    const int nodeW = (N + 3) / 4;
    const int scanBlocks = (N + 1023) / 1024;
    const short* Wts[4] = {Wt0, Wt1, Wt2, Wt3};

    // CSR build (parallel scan)
    hipMemsetAsync(deg, 0, (size_t)N * sizeof(int), stream);
    hist_deg<<<edgeBlocks, 256, 0, stream>>>(ei, deg, E, N);
    scan_blk<<<scanBlocks, 256, 0, stream>>>(deg, locals, bsum, N);
    scan_top<<<1, 256, 0, stream>>>(bsum, boff, scanBlocks);
    scan_add<<<(N + 256) / 256, 256, 0, stream>>>(locals, boff, rowstart,
                                                  cursor, N, Etot);
    fill_csr<<<edgeBlocks, 256, 0, stream>>>(ei, cursor, csr, E, N);

    // weight prep + x conversion
    prep_weights<<<dim3(8, 16), 256, 0, stream>>>(W0, W1, W2, W3, res_W,
                                                  lin_W0, lin_W1, Wt0, Wt1,
                                                  Wt2, Wt3, WtR, WtU, WtV, WbT);
    bias_prep<<<1, 128, 0, stream>>>(lin_b0, bias128);
    convert_x<<<(N * 128 / 4 + 255) / 256, 256, 0, stream>>>(x, xb, N * 128);

    for (int i = 0; i < 4; ++i) {
        if (i == 0)
            mfma_gemm<128, 16, 1><<<gemmBlocks, 256, 0, stream>>>(
                xb, Wt0, nullptr, Hq, a_src, a_dst, Ssrc, Sdst, nullptr,
                nullptr, N);
        else
            mfma_gemm<64, 16, 1><<<gemmBlocks, 256, 0, stream>>>(
                featb, Wts[i], nullptr, Hq, a_src + i * 256, a_dst + i * 256,
                Ssrc, Sdst, nullptr, nullptr, N);
        if (i == 0)  // residual projection (reads xb; precedes gather's featb write)
            mfma_gemm<128, 4, 0><<<gemmBlocks, 256, 0, stream>>>(
                xb, WtR, res_b, nullptr, nullptr, nullptr, nullptr, nullptr,
                res, nullptr, N);
        const float* resid = (i == 0) ? res : feat;
        gat_gather<<<nodeW, 256, 0, stream>>>(csr, rowstart, Ssrc, Sdst, Hq,
                                              gat_b + i * 64, resid, feat,
                                              featb, N);
    }

    // edge classifier heads, single GEMM: UV = feat@[W0_top|W0_bot] + [b0|0]
    mfma_gemm<64, 8, 2><<<gemmBlocks, 256, 0, stream>>>(
        featb, WtU, bias128, nullptr, nullptr, nullptr, nullptr, nullptr,
        nullptr, UVb, N);
    edge_mlp3<<<(E + 63) / 64, 256, 0, stream>>>(
        ei, (const unsigned*)UVb, WbT, lin_b1, lin_W2, lin_b2, out, E);
}

// Round 7
// 353.325 us; speedup vs baseline: 3.5915x; 1.0104x over previous
//
#include <hip/hip_runtime.h>
#include <hip/hip_bf16.h>

#define NSLOPE 0.2f

typedef short bf16x8 __attribute__((ext_vector_type(8)));
typedef float f32x4 __attribute__((ext_vector_type(4)));

__device__ __forceinline__ unsigned short f2b(float f) {
    unsigned u = __float_as_uint(f);
    unsigned r = (u + 0x7FFFu + ((u >> 16) & 1u)) >> 16;
    return (unsigned short)r;
}
__device__ __forceinline__ float b2f_lo(unsigned w) {
    return __uint_as_float(w << 16);
}
__device__ __forceinline__ float b2f_hi(unsigned w) {
    return __uint_as_float(w & 0xFFFF0000u);
}
__device__ __forceinline__ float b2f_s(short s) {
    return __uint_as_float(((unsigned)(unsigned short)s) << 16);
}

// ---------------- CSR build -------------------------------------------------

__global__ __launch_bounds__(256) void hist_deg(const int* __restrict__ ei,
                                                int* __restrict__ deg, int E,
                                                int n) {
    int t = blockIdx.x * 256 + threadIdx.x;
    int Etot = E + n;
    if (t >= Etot) return;
    int d = (t < E) ? ei[E + t] : (t - E);
    atomicAdd(&deg[d], 1);
}

__global__ __launch_bounds__(256) void scan_blk(const int* __restrict__ deg,
                                                int* __restrict__ local,
                                                int* __restrict__ bsum, int n) {
    __shared__ int sm[256];
    const int base = blockIdx.x * 1024;
    const int t = threadIdx.x;
    const int i0 = base + t * 4;
    int v0 = 0, v1 = 0, v2 = 0, v3 = 0;
    if (i0 + 3 < n) {
        int4 v = *(const int4*)(deg + i0);
        v0 = v.x; v1 = v.y; v2 = v.z; v3 = v.w;
    } else {
        if (i0 < n) v0 = deg[i0];
        if (i0 + 1 < n) v1 = deg[i0 + 1];
        if (i0 + 2 < n) v2 = deg[i0 + 2];
    }
    int s = v0 + v1 + v2 + v3;
    sm[t] = s;
    __syncthreads();
    for (int off = 1; off < 256; off <<= 1) {
        int val = (t >= off) ? sm[t - off] : 0;
        __syncthreads();
        sm[t] += val;
        __syncthreads();
    }
    int ex = sm[t] - s;
    if (t == 255) bsum[blockIdx.x] = sm[255];
    if (i0 < n) local[i0] = ex;
    if (i0 + 1 < n) local[i0 + 1] = ex + v0;
    if (i0 + 2 < n) local[i0 + 2] = ex + v0 + v1;
    if (i0 + 3 < n) local[i0 + 3] = ex + v0 + v1 + v2;
}

__global__ __launch_bounds__(256) void scan_top(const int* __restrict__ bsum,
                                                int* __restrict__ boff,
                                                int nb) {
    __shared__ int sm[256];
    const int t = threadIdx.x;
    int s = (t < nb) ? bsum[t] : 0;
    sm[t] = s;
    __syncthreads();
    for (int off = 1; off < 256; off <<= 1) {
        int val = (t >= off) ? sm[t - off] : 0;
        __syncthreads();
        sm[t] += val;
        __syncthreads();
    }
    if (t < nb) boff[t] = sm[t] - s;
}

__global__ __launch_bounds__(256) void scan_add(const int* __restrict__ local,
                                                const int* __restrict__ boff,
                                                int* __restrict__ rowstart,
                                                int* __restrict__ cursor,
                                                int n, int Etot) {
    int i = blockIdx.x * 256 + threadIdx.x;
    if (i > n) return;
    if (i == n) {
        rowstart[n] = Etot;
        return;
    }
    int v = local[i] + boff[i >> 10];
    rowstart[i] = v;
    cursor[i] = v;
}

// writes (src,dst) pairs in dst-sorted CSR order
__global__ __launch_bounds__(256) void fill_csr(const int* __restrict__ ei,
                                                int* __restrict__ cursor,
                                                int2* __restrict__ csr2, int E,
                                                int n) {
    int t = blockIdx.x * 256 + threadIdx.x;
    int Etot = E + n;
    if (t >= Etot) return;
    int s, d;
    if (t < E) { s = ei[t]; d = ei[E + t]; } else { s = d = t - E; }
    int pos = atomicAdd(&cursor[d], 1);
    csr2[pos] = make_int2(s, d);
}

// ---------------- weight prep: fp32 [K][NC] -> bf16 [NC][K] (transposed) ----
__global__ __launch_bounds__(256) void prep_weights(
    const float* __restrict__ W0, const float* __restrict__ W1,
    const float* __restrict__ W2, const float* __restrict__ W3,
    const float* __restrict__ resW, const float* __restrict__ linW0,
    const float* __restrict__ linW1, const float* __restrict__ linB0,
    short* __restrict__ Wt0, short* __restrict__ Wt1, short* __restrict__ Wt2,
    short* __restrict__ Wt3, short* __restrict__ WtR, short* __restrict__ WtU,
    short* __restrict__ WtV, short* __restrict__ WbT,
    float* __restrict__ bias128) {
    const float* src;
    short* dst;
    int K, NC, rowoff = 0;
    switch (blockIdx.x) {
        case 0: src = W0; dst = Wt0; K = 128; NC = 256; break;
        case 1: src = W1; dst = Wt1; K = 64; NC = 256; break;
        case 2: src = W2; dst = Wt2; K = 64; NC = 256; break;
        case 3: src = W3; dst = Wt3; K = 64; NC = 256; break;
        case 4: src = resW; dst = WtR; K = 128; NC = 64; break;
        case 5: src = linW0; dst = WtU; K = 64; NC = 64; break;
        case 6: src = linW0; dst = WtV; K = 64; NC = 64; rowoff = 64; break;
        case 7: src = linW1; dst = WbT; K = 64; NC = 64; break;
        default: {  // bias pad: [b0 | 0]
            if (blockIdx.y == 0 && threadIdx.x < 128)
                bias128[threadIdx.x] =
                    (threadIdx.x < 64) ? linB0[threadIdx.x] : 0.f;
            return;
        }
    }
    for (int idx = blockIdx.y * 256 + threadIdx.x; idx < K * NC;
         idx += 256 * 16) {
        int k = idx / NC, nn = idx - k * NC;
        dst[nn * K + k] = (short)f2b(src[(k + rowoff) * NC + nn]);
    }
}

__global__ __launch_bounds__(256) void convert_x(const float* __restrict__ x,
                                                 short* __restrict__ xb,
                                                 int total) {
    int idx = (blockIdx.x * 256 + threadIdx.x) * 4;
    if (idx >= total) return;
    float4 v = *(const float4*)(x + idx);
    ushort4 o;
    o.x = f2b(v.x); o.y = f2b(v.y); o.z = f2b(v.z); o.w = f2b(v.w);
    *(ushort4*)(xb + idx) = o;
}

// ---------------- MFMA node GEMM -------------------------------------------
// OM=0: OutF fp32 (+bias); OM=1: Hq pack + fused attn scores; OM=2: OutB bf16
template <int K, int NG, int OM>
__global__ __launch_bounds__(256) void mfma_gemm(
    const short* __restrict__ Xb, const short* __restrict__ Wt,
    const float* __restrict__ bias, uint2* __restrict__ Hq,
    const float* __restrict__ as_l, const float* __restrict__ ad_l,
    float* __restrict__ Ssrc, float* __restrict__ Sdst,
    float* __restrict__ OutF, short* __restrict__ OutB, int n) {
    constexpr int XSTR = K + 8;
    constexpr int NC = NG * 16;
    __shared__ __align__(16) short Xs[64 * XSTR];
    __shared__ __align__(16) short Ws[NC * 40];
    const int tid = threadIdx.x;
    const int nb = blockIdx.x * 64;
    constexpr int CH = K / 8;
    for (int idx = tid; idx < 64 * CH; idx += 256) {
        int row = idx / CH, c = idx - row * CH;
        uint4 v = make_uint4(0, 0, 0, 0);
        if (nb + row < n)
            v = *(const uint4*)(Xb + (size_t)(nb + row) * K + c * 8);
        *(uint4*)(Xs + row * XSTR + c * 8) = v;
    }
    const int wid = tid >> 6;
    const int lane = tid & 63;
    const int t = lane & 15, quad = lane >> 4;
    f32x4 acc[NG];
#pragma unroll
    for (int g = 0; g < NG; ++g) acc[g] = (f32x4){0.f, 0.f, 0.f, 0.f};
#pragma unroll 1
    for (int kc = 0; kc < K / 32; ++kc) {
        __syncthreads();
        for (int idx = tid; idx < NC * 4; idx += 256) {
            int row = idx >> 2, c = idx & 3;
            uint4 v = *(const uint4*)(Wt + (size_t)row * K + kc * 32 + c * 8);
            *(uint4*)(Ws + row * 40 + c * 8) = v;
        }
        __syncthreads();
        bf16x8 a =
            *(const bf16x8*)(Xs + (wid * 16 + t) * XSTR + kc * 32 + quad * 8);
#pragma unroll
        for (int g = 0; g < NG; ++g) {
            bf16x8 b = *(const bf16x8*)(Ws + (g * 16 + t) * 40 + quad * 8);
            acc[g] = __builtin_amdgcn_mfma_f32_16x16x32_bf16(a, b, acc[g], 0, 0, 0);
        }
    }
    if (OM == 1) {
#pragma unroll
        for (int r = 0; r < 4; ++r) {
            int node = nb + wid * 16 + quad * 4 + r;
            if (node >= n) continue;
#pragma unroll
            for (int g = 0; g < 4; ++g) {
                unsigned p01 = ((unsigned)f2b(acc[g + 4][r]) << 16) |
                               (unsigned)f2b(acc[g][r]);
                unsigned p23 = ((unsigned)f2b(acc[g + 12][r]) << 16) |
                               (unsigned)f2b(acc[g + 8][r]);
                Hq[(size_t)node * 64 + g * 16 + t] = make_uint2(p01, p23);
            }
        }
        float asv[16], adv[16];
#pragma unroll
        for (int G = 0; G < 16; ++G) {
            asv[G] = as_l[G * 16 + t];
            adv[G] = ad_l[G * 16 + t];
        }
#pragma unroll
        for (int r = 0; r < 4; ++r) {
            int node = nb + wid * 16 + quad * 4 + r;
            float pv[8];
#pragma unroll
            for (int h = 0; h < 4; ++h) {
                float ps = 0.f, pd = 0.f;
#pragma unroll
                for (int j = 0; j < 4; ++j) {
                    float a = acc[h * 4 + j][r];
                    ps += a * asv[h * 4 + j];
                    pd += a * adv[h * 4 + j];
                }
                pv[h] = ps;
                pv[4 + h] = pd;
            }
#pragma unroll
            for (int off = 1; off < 16; off <<= 1) {
#pragma unroll
                for (int i = 0; i < 8; ++i) pv[i] += __shfl_xor(pv[i], off, 64);
            }
            if (t == 0 && node < n) {
                *(float4*)&Ssrc[node * 4] =
                    make_float4(pv[0], pv[1], pv[2], pv[3]);
                *(float4*)&Sdst[node * 4] =
                    make_float4(pv[4], pv[5], pv[6], pv[7]);
            }
        }
    } else {
        float bv[NG];
#pragma unroll
        for (int g = 0; g < NG; ++g) bv[g] = bias ? bias[g * 16 + t] : 0.f;
#pragma unroll
        for (int r = 0; r < 4; ++r) {
            int node = nb + wid * 16 + quad * 4 + r;
            if (node >= n) continue;
            if (OM == 0) {
#pragma unroll
                for (int g = 0; g < NG; ++g)
                    OutF[(size_t)node * NC + g * 16 + t] = acc[g][r] + bv[g];
            } else {
#pragma unroll
                for (int g = 0; g < NG; ++g)
                    OutB[(size_t)node * NC + g * 16 + t] =
                        (short)f2b(acc[g][r] + bv[g]);
            }
        }
    }
}

// ---------------- per-edge softmax numerators (CSR order) -------------------
// p4[e] = exp(leaky_relu(Ssrc[s] + Sdst[d]))  (no max-sub: scores O(1))
__global__ __launch_bounds__(256) void edge_scores(
    const int2* __restrict__ csr2, const float* __restrict__ Ssrc,
    const float* __restrict__ Sdst, float4* __restrict__ p4, int Etot) {
    int e = blockIdx.x * 256 + threadIdx.x;
    if (e >= Etot) return;
    int2 sd = csr2[e];
    float4 ss = *(const float4*)&Ssrc[sd.x * 4];
    float4 dd = *(const float4*)&Sdst[sd.y * 4];
    float c0 = ss.x + dd.x, c1 = ss.y + dd.y, c2 = ss.z + dd.z,
          c3 = ss.w + dd.w;
    c0 = c0 > 0.f ? c0 : NSLOPE * c0;
    c1 = c1 > 0.f ? c1 : NSLOPE * c1;
    c2 = c2 > 0.f ? c2 : NSLOPE * c2;
    c3 = c3 > 0.f ? c3 : NSLOPE * c3;
    p4[e] = make_float4(__expf(c0), __expf(c1), __expf(c2), __expf(c3));
}

// ---------------- fused GAT aggregate + epilogue (gather) -------------------
// One wave per dst node. Per edge: wave-uniform (csr2, p4) loads + one 8B
// Hq gather + 8 FMA. No shuffles/exp on the critical path.
__global__ __launch_bounds__(256) void gat_gather(
    const int2* __restrict__ csr2, const int* __restrict__ rowstart,
    const float4* __restrict__ p4, const uint2* __restrict__ Hq,
    const float* __restrict__ gb, const float* __restrict__ resid,
    float* __restrict__ featOut, short* __restrict__ featB, int n) {
    const int wid = threadIdx.x >> 6;
    const int lane = threadIdx.x & 63;
    const int node = blockIdx.x * 4 + wid;
    if (node >= n) return;
    const int start = __builtin_amdgcn_readfirstlane(rowstart[node]);
    const int end = __builtin_amdgcn_readfirstlane(rowstart[node + 1]);
    float u0 = 0.f, u1 = 0.f, u2 = 0.f, u3 = 0.f;
    float z0 = 0.f, z1 = 0.f, z2 = 0.f, z3 = 0.f;
#pragma unroll 4
    for (int e = start; e < end; ++e) {
        int sj = csr2[e].x;
        float4 p = p4[e];
        uint2 hv = Hq[(size_t)sj * 64 + lane];
        u0 += p.x * b2f_lo(hv.x);
        u1 += p.y * b2f_hi(hv.x);
        u2 += p.z * b2f_lo(hv.y);
        u3 += p.w * b2f_hi(hv.y);
        z0 += p.x; z1 += p.y; z2 += p.z; z3 += p.w;
    }
    float val = 0.25f * (u0 / z0 + u1 / z1 + u2 / z2 + u3 / z3) + gb[lane] +
                resid[(size_t)node * 64 + lane];
    val = val > 0.f ? val : expm1f(val);
    featOut[(size_t)node * 64 + lane] = val;
    featB[(size_t)node * 64 + lane] = (short)f2b(val);
}

// ---------------- edge classifier (MFMA) ------------------------------------
// UV: [node][128] bf16 (U cols 0..63 incl b0, V cols 64..127)
__global__ __launch_bounds__(256) void edge_mlp3(
    const int* __restrict__ ei, const unsigned* __restrict__ UV,
    const short* __restrict__ WbT, const float* __restrict__ bb,
    const float* __restrict__ Wc, const float* __restrict__ bc,
    float* __restrict__ out, int E) {
    __shared__ __align__(16) short t1b[64 * 72];
    __shared__ __align__(16) short wbs[64 * 72];
    const int tid = threadIdx.x;
    const int eBase = blockIdx.x * 64;
    for (int idx = tid; idx < 512; idx += 256) {
        int row = idx >> 3, c = idx & 7;
        *(uint4*)(wbs + row * 72 + c * 8) =
            *(const uint4*)(WbT + row * 64 + c * 8);
    }
    {
        const int j = tid & 31;
        const int eg = tid >> 5;
        int rr[8], cc[8];
#pragma unroll
        for (int it = 0; it < 8; ++it) {
            int e = eBase + it * 8 + eg;
            rr[it] = (e < E) ? ei[e] : 0;
            cc[it] = (e < E) ? ei[E + e] : 0;
        }
#pragma unroll
        for (int it = 0; it < 8; ++it) {
            unsigned uu = UV[(size_t)rr[it] * 64 + j];
            unsigned vv = UV[(size_t)cc[it] * 64 + 32 + j];
            float lo = fmaxf(b2f_lo(uu) + b2f_lo(vv), 0.f);
            float hi = fmaxf(b2f_hi(uu) + b2f_hi(vv), 0.f);
            *(unsigned*)(t1b + (it * 8 + eg) * 72 + j * 2) =
                ((unsigned)f2b(hi) << 16) | (unsigned)f2b(lo);
        }
    }
    __syncthreads();
    const int w = tid >> 6, lane = tid & 63;
    const int t = lane & 15, quad = lane >> 4;
    f32x4 acc[4];
#pragma unroll
    for (int g = 0; g < 4; ++g) acc[g] = (f32x4){0.f, 0.f, 0.f, 0.f};
#pragma unroll
    for (int kc = 0; kc < 2; ++kc) {
        bf16x8 a = *(const bf16x8*)(t1b + (w * 16 + t) * 72 + kc * 32 + quad * 8);
#pragma unroll
        for (int g = 0; g < 4; ++g) {
            bf16x8 b = *(const bf16x8*)(wbs + (g * 16 + t) * 72 + kc * 32 + quad * 8);
            acc[g] = __builtin_amdgcn_mfma_f32_16x16x32_bf16(a, b, acc[g], 0, 0, 0);
        }
    }
    float wcv[4], bbv[4];
#pragma unroll
    for (int g = 0; g < 4; ++g) {
        wcv[g] = Wc[g * 16 + t];
        bbv[g] = bb[g * 16 + t];
    }
    const float bcv = bc[0];
#pragma unroll
    for (int r = 0; r < 4; ++r) {
        int el = w * 16 + quad * 4 + r;
        float part = 0.f;
#pragma unroll
        for (int g = 0; g < 4; ++g) {
            float t1v = b2f_s(t1b[el * 72 + g * 16 + t]);
            float t2 = fmaxf(acc[g][r] + bbv[g] + t1v, 0.f);
            part += t2 * wcv[g];
        }
        part += __shfl_xor(part, 1, 64);
        part += __shfl_xor(part, 2, 64);
        part += __shfl_xor(part, 4, 64);
        part += __shfl_xor(part, 8, 64);
        int e = eBase + el;
        if (t == 0 && e < E) out[e] = part + bcv;
    }
}

extern "C" void kernel_launch(void* const* d_in, const int* in_sizes, int n_in,
                              void* d_out, int out_size, void* d_ws,
                              size_t ws_size, hipStream_t stream) {
    const float* x = (const float*)d_in[0];
    const int* ei = (const int*)d_in[1];
    const float* W0 = (const float*)d_in[2];
    const float* W1 = (const float*)d_in[3];
    const float* W2 = (const float*)d_in[4];
    const float* W3 = (const float*)d_in[5];
    const float* a_src = (const float*)d_in[6];
    const float* a_dst = (const float*)d_in[7];
    const float* gat_b = (const float*)d_in[8];
    const float* res_W = (const float*)d_in[9];
    const float* res_b = (const float*)d_in[10];
    const float* lin_W0 = (const float*)d_in[11];
    const float* lin_b0 = (const float*)d_in[12];
    const float* lin_W1 = (const float*)d_in[13];
    const float* lin_b1 = (const float*)d_in[14];
    const float* lin_W2 = (const float*)d_in[15];
    const float* lin_b2 = (const float*)d_in[16];
    float* out = (float*)d_out;

    const int N = in_sizes[0] / 128;  // 20000
    const int E = in_sizes[1] / 2;    // 320000
    const int Etot = E + N;

    float* ws = (float*)d_ws;
    uint2* Hq = (uint2*)ws;                            // N*64 uint2
    float* feat = (float*)(Hq + (size_t)N * 64);       // N*64 f32
    float* res = feat + (size_t)N * 64;                // N*64 f32
    short* xb = (short*)(res + (size_t)N * 64);        // N*128 bf16
    short* featb = xb;                                 // alias (N*64 bf16)
    float* Ssrc = (float*)(xb + (size_t)N * 128);      // N*4
    float* Sdst = Ssrc + (size_t)N * 4;                // N*4
    short* Wt0 = (short*)(Sdst + (size_t)N * 4);       // 256*128
    short* Wt1 = Wt0 + 256 * 128;                      // 256*64
    short* Wt2 = Wt1 + 256 * 64;
    short* Wt3 = Wt2 + 256 * 64;
    short* WtR = Wt3 + 256 * 64;                       // 64*128
    short* WtU = WtR + 64 * 128;                       // 64*64 (U cols)
    short* WtV = WtU + 64 * 64;                        // 64*64 (V cols, contig)
    short* WbT = WtV + 64 * 64;                        // 64*64
    int* deg = (int*)(WbT + 64 * 64);                  // N
    int* rowstart = deg + N;                           // N+1
    int* cursor = rowstart + N + 1;                    // N
    int* locals = cursor + N;                          // N
    int* bsum = locals + N;                            // 256
    int* boff = bsum + 256;                            // 256
    float* bias128 = (float*)(boff + 256);             // 128
    int2* csr2 = (int2*)(((size_t)(bias128 + 128) + 15) & ~(size_t)15);  // Etot
    float4* p4 = (float4*)(((size_t)(csr2 + Etot) + 15) & ~(size_t)15);  // Etot
    short* UVb = (short*)Hq;                           // alias, N*128 bf16

    const int gemmBlocks = (N + 63) / 64;
    const int edgeBlocks = (Etot + 255) / 256;
    const int nodeW = (N + 3) / 4;
    const int scanBlocks = (N + 1023) / 1024;
    const short* Wts[4] = {Wt0, Wt1, Wt2, Wt3};

    // CSR build (parallel scan)
    hipMemsetAsync(deg, 0, (size_t)N * sizeof(int), stream);
    hist_deg<<<edgeBlocks, 256, 0, stream>>>(ei, deg, E, N);
    scan_blk<<<scanBlocks, 256, 0, stream>>>(deg, locals, bsum, N);
    scan_top<<<1, 256, 0, stream>>>(bsum, boff, scanBlocks);
    scan_add<<<(N + 256) / 256, 256, 0, stream>>>(locals, boff, rowstart,
                                                  cursor, N, Etot);
    fill_csr<<<edgeBlocks, 256, 0, stream>>>(ei, cursor, csr2, E, N);

    // weight prep + x conversion
    prep_weights<<<dim3(9, 16), 256, 0, stream>>>(
        W0, W1, W2, W3, res_W, lin_W0, lin_W1, lin_b0, Wt0, Wt1, Wt2, Wt3,
        WtR, WtU, WtV, WbT, bias128);
    convert_x<<<(N * 128 / 4 + 255) / 256, 256, 0, stream>>>(x, xb, N * 128);

    for (int i = 0; i < 4; ++i) {
        if (i == 0)
            mfma_gemm<128, 16, 1><<<gemmBlocks, 256, 0, stream>>>(
                xb, Wt0, nullptr, Hq, a_src, a_dst, Ssrc, Sdst, nullptr,
                nullptr, N);
        else
            mfma_gemm<64, 16, 1><<<gemmBlocks, 256, 0, stream>>>(
                featb, Wts[i], nullptr, Hq, a_src + i * 256, a_dst + i * 256,
                Ssrc, Sdst, nullptr, nullptr, N);
        edge_scores<<<edgeBlocks, 256, 0, stream>>>(csr2, Ssrc, Sdst, p4,
                                                    Etot);
        if (i == 0)  // residual projection (reads xb; precedes gather's featb write)
            mfma_gemm<128, 4, 0><<<gemmBlocks, 256, 0, stream>>>(
                xb, WtR, res_b, nullptr, nullptr, nullptr, nullptr, nullptr,
                res, nullptr, N);
        const float* resid = (i == 0) ? res : feat;
        gat_gather<<<nodeW, 256, 0, stream>>>(csr2, rowstart, p4, Hq,
                                              gat_b + i * 64, resid, feat,
                                              featb, N);
    }

    // edge classifier heads, single GEMM: UV = feat@[W0_top|W0_bot] + [b0|0]
    mfma_gemm<64, 8, 2><<<gemmBlocks, 256, 0, stream>>>(
        featb, WtU, bias128, nullptr, nullptr, nullptr, nullptr, nullptr,
        nullptr, UVb, N);
    edge_mlp3<<<(E + 63) / 64, 256, 0, stream>>>(
        ei, (const unsigned*)UVb, WbT, lin_b1, lin_W2, lin_b2, out, E);
}